// Round 3
// baseline (4782.511 us; speedup 1.0000x reference)
//
#include <hip/hip_runtime.h>
#include <hip/hip_bf16.h>
#include <math.h>

typedef __hip_bfloat16 bf16;

__device__ __forceinline__ float b2f(bf16 v){ return __bfloat162float(v); }
__device__ __forceinline__ bf16  f2b(float v){ return __float2bfloat16(v); }
__device__ __forceinline__ float cvt(float v){ return v; }
__device__ __forceinline__ float cvt(bf16 v){ return __bfloat162float(v); }
__device__ __forceinline__ float bfbits(unsigned u){ return __uint_as_float(u << 16); }
__device__ __forceinline__ unsigned short b2us(bf16 v){ union { bf16 b; unsigned short u; } c; c.b = v; return c.u; }
__device__ __forceinline__ void unpack8(uint4 q, float* f){
  f[0]=bfbits(q.x&0xffffu); f[1]=bfbits(q.x>>16);
  f[2]=bfbits(q.y&0xffffu); f[3]=bfbits(q.y>>16);
  f[4]=bfbits(q.z&0xffffu); f[5]=bfbits(q.z>>16);
  f[6]=bfbits(q.w&0xffffu); f[7]=bfbits(q.w>>16);
}
__device__ __forceinline__ uint4 pack8f(const float* f){
  uint4 q;
  q.x = (unsigned)b2us(f2b(f[0])) | ((unsigned)b2us(f2b(f[1]))<<16);
  q.y = (unsigned)b2us(f2b(f[2])) | ((unsigned)b2us(f2b(f[3]))<<16);
  q.z = (unsigned)b2us(f2b(f[4])) | ((unsigned)b2us(f2b(f[5]))<<16);
  q.w = (unsigned)b2us(f2b(f[6])) | ((unsigned)b2us(f2b(f[7]))<<16);
  return q;
}

#define NTOK 1280
#define LSEQ 8960
#define CHLEN 140
#define ATT_SCALE 0.1889822365046136f   /* 28^-0.5 */

/* ---------------- generic tiled GEMM: C(f32) = A @ B ---------------- */
template<typename TA, typename TB>
__global__ __launch_bounds__(256) void gemm_kernel(const TA* __restrict__ A, const TB* __restrict__ B,
                                                   float* __restrict__ C, int M, int N, int K) {
  __shared__ float As[16][64];
  __shared__ float Bs[16][64];
  const int tid = threadIdx.x;
  const int tx = tid & 15, ty = tid >> 4;
  const int m0 = blockIdx.y * 64, n0 = blockIdx.x * 64;
  const int ar = tid >> 4, ac = tid & 15;
  const int bn = tid & 63, bk = tid >> 6;
  float acc[4][4] = {};
  for (int k0 = 0; k0 < K; k0 += 16) {
#pragma unroll
    for (int s = 0; s < 4; ++s) {
      int m = m0 + ar + 16*s;
      float v = 0.f;
      if (m < M && (k0+ac) < K) v = cvt(A[(size_t)m*K + k0 + ac]);
      As[ac][ar + 16*s] = v;
    }
#pragma unroll
    for (int s = 0; s < 4; ++s) {
      int kk = bk + 4*s;
      float v = 0.f;
      if ((n0+bn) < N && (k0+kk) < K) v = cvt(B[(size_t)(k0+kk)*N + n0 + bn]);
      Bs[kk][bn] = v;
    }
    __syncthreads();
#pragma unroll
    for (int kk = 0; kk < 16; ++kk) {
      float a[4], b[4];
#pragma unroll
      for (int i = 0; i < 4; ++i) a[i] = As[kk][ty*4+i];
#pragma unroll
      for (int j = 0; j < 4; ++j) b[j] = Bs[kk][tx*4+j];
#pragma unroll
      for (int i = 0; i < 4; ++i)
#pragma unroll
        for (int j = 0; j < 4; ++j) acc[i][j] = fmaf(a[i], b[j], acc[i][j]);
    }
    __syncthreads();
  }
#pragma unroll
  for (int i = 0; i < 4; ++i) {
    int m = m0 + ty*4 + i;
    if (m >= M) continue;
#pragma unroll
    for (int j = 0; j < 4; ++j) {
      int n = n0 + tx*4 + j;
      if (n < N) C[(size_t)m*N + n] = acc[i][j];
    }
  }
}

__global__ __launch_bounds__(256) void zero_kernel(float* __restrict__ p, int n) {
  int i = blockIdx.x*256 + threadIdx.x;
  if (i < n) p[i] = 0.f;
}

/* ------------- stage A: column sum-of-squares for q (224) and k (first 224 of kv) ------------- */
__global__ __launch_bounds__(256) void colnorm_kernel(const float* __restrict__ qb, const float* __restrict__ kvb,
                                                      float* __restrict__ nqs, float* __restrict__ nks) {
  const int b  = blockIdx.x >> 4;
  const int nc = blockIdx.x & 15;
  const int tid = threadIdx.x;
  __shared__ float lq[224], lk[224];
  if (tid < 224) { lq[tid] = 0.f; lk[tid] = 0.f; }
  __syncthreads();
  const int n0 = nc * 80;
  for (int idx = tid; idx < 80*224; idx += 256) {
    int n = n0 + idx / 224, c = idx % 224;
    float v = qb[((size_t)(b*NTOK + n))*224 + c];
    atomicAdd(&lq[c], v*v);
    float w = kvb[((size_t)(b*NTOK + n))*448 + c];
    atomicAdd(&lk[c], w*w);
  }
  __syncthreads();
  if (tid < 224) {
    atomicAdd(&nqs[b*224 + tid], lq[tid]);
    atomicAdd(&nks[b*224 + tid], lk[tid]);
  }
}

/* ------------- stage A: 28x28 gram + softmax per (b, head) ------------- */
__global__ __launch_bounds__(256) void gram_kernel(const float* __restrict__ qb, const float* __restrict__ kvb,
                                                   const float* __restrict__ nqs, const float* __restrict__ nks,
                                                   float* __restrict__ attnA) {
  const int b = blockIdx.x >> 3, hd = blockIdx.x & 7;
  const int tid = threadIdx.x;
  __shared__ float kt[32][28];
  __shared__ float qt[32][28];
  __shared__ float sc[784];
  float acc[4] = {0.f,0.f,0.f,0.f};
  for (int nt = 0; nt < NTOK; nt += 32) {
    __syncthreads();
    for (int idx = tid; idx < 896; idx += 256) {
      int r = idx / 28, c = idx % 28;
      kt[r][c] = kvb[((size_t)(b*NTOK + nt + r))*448 + hd*28 + c];
      qt[r][c] = qb [((size_t)(b*NTOK + nt + r))*224 + hd*28 + c];
    }
    __syncthreads();
#pragma unroll
    for (int p = 0; p < 4; ++p) {
      int idx = tid + p*256;
      if (idx < 784) {
        int i = idx / 28, j = idx % 28;
        float s = 0.f;
#pragma unroll
        for (int r = 0; r < 32; ++r) s = fmaf(kt[r][i], qt[r][j], s);
        acc[p] += s;
      }
    }
  }
  __syncthreads();
#pragma unroll
  for (int p = 0; p < 4; ++p) {
    int idx = tid + p*256;
    if (idx < 784) {
      int i = idx / 28, j = idx % 28;
      float nk = fmaxf(sqrtf(nks[b*224 + hd*28 + i]), 1e-12f);
      float nq = fmaxf(sqrtf(nqs[b*224 + hd*28 + j]), 1e-12f);
      sc[idx] = acc[p] * ATT_SCALE / (nk * nq);
    }
  }
  __syncthreads();
  if (tid < 28) {
    int i = tid;
    float mx = -1e30f;
#pragma unroll
    for (int j = 0; j < 28; ++j) mx = fmaxf(mx, sc[i*28+j]);
    float e[28]; float s = 0.f;
#pragma unroll
    for (int j = 0; j < 28; ++j) { e[j] = expf(sc[i*28+j] - mx); s += e[j]; }
    float inv = 1.f / s;
#pragma unroll
    for (int j = 0; j < 28; ++j) attnA[(size_t)blockIdx.x*784 + i*28 + j] = e[j]*inv;
  }
}

/* ------------- stage A: apply attention over channels + residual ------------- */
__global__ __launch_bounds__(256) void applyattn_kernel(const float* __restrict__ attnA, const float* __restrict__ kvb,
                                                        const float* __restrict__ x, float* __restrict__ x1) {
  const int bhd = blockIdx.x;
  const int b = bhd >> 3, hd = bhd & 7;
  const int tid = threadIdx.x;
  __shared__ float a[784];
  for (int idx = tid; idx < 784; idx += 256) a[idx] = attnA[(size_t)bhd*784 + idx];
  __syncthreads();
  const int i = tid % 28;
  const int n = blockIdx.y * 9 + tid / 28;
  if (tid < 252 && n < NTOK) {
    const float* vrow = &kvb[((size_t)(b*NTOK + n))*448 + 224 + hd*28];
    float s = 0.f;
#pragma unroll
    for (int j = 0; j < 28; ++j) s = fmaf(a[i*28+j], vrow[j], s);
    size_t o = ((size_t)(b*NTOK + n))*224 + hd*28 + i;
    x1[o] = s + x[o];
  }
}

/* ------------- mamba: LN + in_proj (xi half) ----- xi time-major [b][t][64] ------------- */
__global__ __launch_bounds__(256) void mamba_in_kernel(const float* __restrict__ x1, const float* __restrict__ lng,
                                                       const float* __restrict__ lnb, const float* __restrict__ Wip,
                                                       bf16* __restrict__ xi) {
  __shared__ float W[2048];
  __shared__ float g[32], bb[32];
  const int tid = threadIdx.x;
  const int b = blockIdx.y;
  const int t = blockIdx.x*256 + tid;
  for (int idx = tid; idx < 2048; idx += 256) {
    int m = idx >> 6, d = idx & 63;
    W[idx] = Wip[m*128 + d];
  }
  if (tid < 32) { g[tid] = lng[tid]; bb[tid] = lnb[tid]; }
  __syncthreads();
  float xv[32];
  float mean = 0.f;
#pragma unroll
  for (int m = 0; m < 32; ++m) { xv[m] = x1[((size_t)(b*32+m))*LSEQ + t]; mean += xv[m]; }
  mean *= (1.f/32.f);
  float var = 0.f;
#pragma unroll
  for (int m = 0; m < 32; ++m) { float d = xv[m]-mean; var = fmaf(d, d, var); }
  var *= (1.f/32.f);
  const float rstd = rsqrtf(var + 1e-5f);
  float xn[32];
#pragma unroll
  for (int m = 0; m < 32; ++m) xn[m] = (xv[m]-mean)*rstd*g[m] + bb[m];
  bf16* row = xi + ((size_t)b*LSEQ + t)*64;
#pragma unroll
  for (int gi = 0; gi < 8; ++gi) {
    float sv[8];
#pragma unroll
    for (int j = 0; j < 8; ++j) {
      int d = gi*8 + j;
      float s = 0.f;
#pragma unroll
      for (int m = 0; m < 32; ++m) s = fmaf(xn[m], W[m*64+d], s);
      sv[j] = s;
    }
    *(uint4*)(row + gi*8) = pack8f(sv);
  }
}

/* ------------- mamba: causal depthwise conv + silu + x_proj + dt (time-major) ------------- */
__global__ __launch_bounds__(256) void mamba_conv_kernel(const bf16* __restrict__ xi, const float* __restrict__ convW,
    const float* __restrict__ convB, const float* __restrict__ xpW, const float* __restrict__ dtW,
    const float* __restrict__ dtB, bf16* __restrict__ xc, bf16* __restrict__ dts,
    bf16* __restrict__ Bc, bf16* __restrict__ Ccs) {
  __shared__ float Wc[256], bcs[64], Wxp[2176], Wdt[128], bdt[64];
  const int tid = threadIdx.x;
  if (tid < 256) Wc[tid] = convW[tid];
  for (int idx = tid; idx < 2176; idx += 256) Wxp[idx] = xpW[idx];
  if (tid < 128) Wdt[tid] = dtW[tid];
  if (tid < 64) { bcs[tid] = convB[tid]; bdt[tid] = dtB[tid]; }
  __syncthreads();
  const int b = blockIdx.y;
  const int t = blockIdx.x*256 + tid;
  const size_t rowb = ((size_t)b*LSEQ + t)*64;
  float d0 = 0.f, d1 = 0.f;
  float s1[16] = {}, s2[16] = {};
  bf16* xcrow = xc + rowb;
#pragma unroll
  for (int gi = 0; gi < 8; ++gi) {
    float xv[4][8];
#pragma unroll
    for (int r = 0; r < 4; ++r) {
      int tt = t - 3 + r;
      if (tt >= 0) {
        uint4 q = *(const uint4*)(xi + ((size_t)b*LSEQ + tt)*64 + gi*8);
        unpack8(q, xv[r]);
      } else {
#pragma unroll
        for (int j = 0; j < 8; ++j) xv[r][j] = 0.f;
      }
    }
    float sv[8];
#pragma unroll
    for (int j = 0; j < 8; ++j) {
      int d = gi*8 + j;
      float s = bcs[d];
      s = fmaf(xv[0][j], Wc[d*4+0], s);
      s = fmaf(xv[1][j], Wc[d*4+1], s);
      s = fmaf(xv[2][j], Wc[d*4+2], s);
      s = fmaf(xv[3][j], Wc[d*4+3], s);
      s = s / (1.f + expf(-s));
      sv[j] = s;
      d0 = fmaf(s, Wxp[d*34+0], d0);
      d1 = fmaf(s, Wxp[d*34+1], d1);
#pragma unroll
      for (int n = 0; n < 16; ++n) {
        s1[n] = fmaf(s, Wxp[d*34+2+n],  s1[n]);
        s2[n] = fmaf(s, Wxp[d*34+18+n], s2[n]);
      }
    }
    *(uint4*)(xcrow + gi*8) = pack8f(sv);
  }
  const size_t tb = ((size_t)b*LSEQ + t)*16;
  *(uint4*)(Bc  + tb)     = pack8f(s1);
  *(uint4*)(Bc  + tb + 8) = pack8f(s1+8);
  *(uint4*)(Ccs + tb)     = pack8f(s2);
  *(uint4*)(Ccs + tb + 8) = pack8f(s2+8);
  bf16* dtrow = dts + rowb;
#pragma unroll
  for (int gi = 0; gi < 8; ++gi) {
    float sv[8];
#pragma unroll
    for (int j = 0; j < 8; ++j) {
      int d = gi*8 + j;
      float v = fmaf(d0, Wdt[d], fmaf(d1, Wdt[64+d], bdt[d]));
      v = (v > 20.f) ? v : log1pf(expf(v));
      sv[j] = v;
    }
    *(uint4*)(dtrow + gi*8) = pack8f(sv);
  }
}

/* ------------- scan pass 1: per-chunk decay product + local final (lane = d) ------------- */
__global__ __launch_bounds__(256) void scan1_kernel(const bf16* __restrict__ dts, const bf16* __restrict__ xc,
    const bf16* __restrict__ Bc, const float* __restrict__ Alog, float* __restrict__ P, float* __restrict__ F) {
  const int w = blockIdx.x*4 + (threadIdx.x >> 6);
  const int d = threadIdx.x & 63;
  const int b = w >> 6, chk = w & 63;
  float A[16];
#pragma unroll
  for (int n = 0; n < 16; ++n) A[n] = -expf(Alog[d*16+n]);
  float Pr[16], Fr[16];
#pragma unroll
  for (int n = 0; n < 16; ++n) { Pr[n] = 1.f; Fr[n] = 0.f; }
  const size_t tbase = (size_t)b*LSEQ + (size_t)chk*CHLEN;
  for (int i = 0; i < CHLEN; ++i) {
    const size_t t = tbase + i;
    float dtv = b2f(dts[t*64 + d]);
    float u   = b2f(xc [t*64 + d]);
    float du  = dtv*u;
    const uint4* bp = (const uint4*)(Bc + t*16);
    float Bv[16]; unpack8(bp[0], Bv); unpack8(bp[1], Bv+8);
#pragma unroll
    for (int n = 0; n < 16; ++n) {
      float a = expf(dtv*A[n]);
      Pr[n] *= a;
      Fr[n] = fmaf(a, Fr[n], du*Bv[n]);
    }
  }
  const size_t o = (((size_t)(b*64 + chk))*64 + d)*16;
  float4* Pp = (float4*)(P + o);
  float4* Fp = (float4*)(F + o);
#pragma unroll
  for (int q = 0; q < 4; ++q) {
    Pp[q] = make_float4(Pr[4*q], Pr[4*q+1], Pr[4*q+2], Pr[4*q+3]);
    Fp[q] = make_float4(Fr[4*q], Fr[4*q+1], Fr[4*q+2], Fr[4*q+3]);
  }
}

/* ------------- scan pass 2: sequential combine across chunks ------------- */
__global__ __launch_bounds__(256) void scan2_kernel(const float* __restrict__ P, const float* __restrict__ F,
                                                    float* __restrict__ H0) {
  const int idx = blockIdx.x*256 + threadIdx.x;   // 32768 = 32 b x 64 d x 16 n
  const int b = idx >> 10, dn = idx & 1023;
  const size_t base = (size_t)b*64*1024 + dn;
  float h = 0.f;
  for (int ch = 0; ch < 64; ++ch) {
    const size_t a = base + (size_t)ch*1024;
    H0[a] = h;
    h = fmaf(P[a], h, F[a]);
  }
}

/* ------------- scan pass 3: replay with correct init, emit y (+ u*Dp), lane = d ------------- */
__global__ __launch_bounds__(256) void scan3_kernel(const bf16* __restrict__ dts, const bf16* __restrict__ xc,
    const bf16* __restrict__ Bc, const bf16* __restrict__ Ccs, const float* __restrict__ Alog,
    const float* __restrict__ Dp, const float* __restrict__ H0, bf16* __restrict__ y) {
  const int w = blockIdx.x*4 + (threadIdx.x >> 6);
  const int d = threadIdx.x & 63;
  const int b = w >> 6, chk = w & 63;
  float A[16];
#pragma unroll
  for (int n = 0; n < 16; ++n) A[n] = -expf(Alog[d*16+n]);
  float h[16];
  const size_t hb = (((size_t)(b*64 + chk))*64 + d)*16;
  const float4* Hp = (const float4*)(H0 + hb);
#pragma unroll
  for (int q = 0; q < 4; ++q) {
    float4 v = Hp[q];
    h[4*q] = v.x; h[4*q+1] = v.y; h[4*q+2] = v.z; h[4*q+3] = v.w;
  }
  const float Dpd = Dp[d];
  const size_t tbase = (size_t)b*LSEQ + (size_t)chk*CHLEN;
  for (int i = 0; i < CHLEN; ++i) {
    const size_t t = tbase + i;
    float dtv = b2f(dts[t*64 + d]);
    float u   = b2f(xc [t*64 + d]);
    float du  = dtv*u;
    const uint4* bp = (const uint4*)(Bc  + t*16);
    const uint4* cp = (const uint4*)(Ccs + t*16);
    float Bv[16], Cv[16];
    unpack8(bp[0], Bv); unpack8(bp[1], Bv+8);
    unpack8(cp[0], Cv); unpack8(cp[1], Cv+8);
    float yv = 0.f;
#pragma unroll
    for (int n = 0; n < 16; ++n) {
      float a = expf(dtv*A[n]);
      h[n] = fmaf(a, h[n], du*Bv[n]);
      yv = fmaf(h[n], Cv[n], yv);
    }
    y[t*64 + d] = f2b(yv + u*Dpd);
  }
}

/* ------------- mamba tail: gate, out_proj, skip, LN, proj, residual (x1 in place) ------------- */
__global__ __launch_bounds__(256) void mamba_out_kernel(float* __restrict__ x1, const bf16* __restrict__ y,
    const float* __restrict__ lng, const float* __restrict__ lnb, const float* __restrict__ Wip,
    const float* __restrict__ Wout, const float* __restrict__ skipp, const float* __restrict__ Wp,
    const float* __restrict__ pbias) {
  __shared__ float Wz[2048];   // in_proj z-half, [m][d]
  __shared__ float Wo[2048];   // out_proj, [d][m]
  __shared__ float Pw[1024];   // proj_W, [m][m2]
  __shared__ float g[32], bb[32], pb[32];
  __shared__ float sskip;
  const int tid = threadIdx.x;
  for (int idx = tid; idx < 2048; idx += 256) {
    int m = idx >> 6, d = idx & 63;
    Wz[m*64+d] = Wip[m*128 + 64 + d];
  }
  for (int idx = tid; idx < 2048; idx += 256) Wo[idx] = Wout[idx];
  for (int idx = tid; idx < 1024; idx += 256) Pw[idx] = Wp[idx];
  if (tid < 32) { g[tid] = lng[tid]; bb[tid] = lnb[tid]; pb[tid] = pbias[tid]; }
  if (tid == 0) sskip = skipp[0];
  __syncthreads();
  const int b = blockIdx.y;
  const int t = blockIdx.x*256 + tid;
  float xv[32];
  float mean = 0.f;
#pragma unroll
  for (int m = 0; m < 32; ++m) { xv[m] = x1[((size_t)(b*32+m))*LSEQ + t]; mean += xv[m]; }
  mean *= (1.f/32.f);
  float var = 0.f;
#pragma unroll
  for (int m = 0; m < 32; ++m) { float d = xv[m]-mean; var = fmaf(d, d, var); }
  var *= (1.f/32.f);
  const float rstd = rsqrtf(var + 1e-5f);
  float xn[32];
#pragma unroll
  for (int m = 0; m < 32; ++m) xn[m] = (xv[m]-mean)*rstd*g[m] + bb[m];
  float out[32] = {};
  const bf16* yrow = y + ((size_t)b*LSEQ + t)*64;
#pragma unroll
  for (int gi = 0; gi < 8; ++gi) {
    uint4 q = *(const uint4*)(yrow + gi*8);
    float yv8[8]; unpack8(q, yv8);
#pragma unroll
    for (int j = 0; j < 8; ++j) {
      int d = gi*8 + j;
      float zd = 0.f;
#pragma unroll
      for (int m = 0; m < 32; ++m) zd = fmaf(xn[m], Wz[m*64+d], zd);
      float gd = yv8[j] * zd / (1.f + expf(-zd));
#pragma unroll
      for (int m = 0; m < 32; ++m) out[m] = fmaf(gd, Wo[d*32+m], out[m]);
    }
  }
#pragma unroll
  for (int m = 0; m < 32; ++m) out[m] = fmaf(sskip, xn[m], out[m]);
  float mean2 = 0.f;
#pragma unroll
  for (int m = 0; m < 32; ++m) mean2 += out[m];
  mean2 *= (1.f/32.f);
  float var2 = 0.f;
#pragma unroll
  for (int m = 0; m < 32; ++m) { float d = out[m]-mean2; var2 = fmaf(d, d, var2); }
  var2 *= (1.f/32.f);
  const float rstd2 = rsqrtf(var2 + 1e-5f);
#pragma unroll
  for (int m = 0; m < 32; ++m) out[m] = (out[m]-mean2)*rstd2*g[m] + bb[m];
  for (int m2 = 0; m2 < 32; ++m2) {
    float r = pb[m2];
#pragma unroll
    for (int m = 0; m < 32; ++m) r = fmaf(out[m], Pw[m*32+m2], r);
    x1[((size_t)(b*32+m2))*LSEQ + t] = r + xv[m2];
  }
}

/* ------------- 5x5x5 conv over (h,w,c), single channel ------------- */
__global__ __launch_bounds__(256) void conv3d_kernel(const float* __restrict__ x2, const float* __restrict__ w,
                                                     const float* __restrict__ bias, float* __restrict__ x3) {
  __shared__ float ww[125];
  __shared__ float b0;
  const int tid = threadIdx.x;
  if (tid < 125) ww[tid] = w[tid];
  if (tid == 0) b0 = bias[0];
  __syncthreads();
  const int gid = blockIdx.x*256 + tid;
  int k = gid % 224; int r = gid / 224;
  int j = r % 40; r /= 40;
  int i = r % 32; int b = r / 32;
  float acc = 0.f;
  for (int di = 0; di < 5; ++di) {
    int ii = i + di - 2; if (ii < 0 || ii >= 32) continue;
    for (int dj = 0; dj < 5; ++dj) {
      int jj = j + dj - 2; if (jj < 0 || jj >= 40) continue;
      const float* row = &x2[(((size_t)(b*32+ii))*40 + jj)*224];
      const float* wr = &ww[(di*5+dj)*5];
#pragma unroll
      for (int dk = 0; dk < 5; ++dk) {
        int kk = k + dk - 2;
        if (kk >= 0 && kk < 224) acc = fmaf(wr[dk], row[kk], acc);
      }
    }
  }
  x3[gid] = acc + b0;
}

/* ------------- DWT + reflect-pad + window partition (all 4 subbands at once) ------------- */
__global__ __launch_bounds__(256) void dwtwin_kernel(const float* __restrict__ x3, bf16* __restrict__ xw) {
  const int gid = blockIdx.x*256 + threadIdx.x;   // < 192*64*224
  const int ch = gid % 224; int r = gid / 224;
  const int tok = r % 64; const int win = r / 64;
  const int b = win / 6, rr = win % 6, wy = rr / 3, wx = rr % 3;
  const int ty = tok >> 3, tx = tok & 7;
  const int i = wy*8 + ty;
  const int jp = wx*8 + tx;
  const int j = (jp < 20) ? jp : (38 - jp);   // reflect pad on the right
  const size_t base = (((size_t)(b*32 + 2*i))*40 + 2*j)*224 + ch;
  const float v00 = x3[base];
  const float v01 = x3[base + 224];
  const float v10 = x3[base + 8960];
  const float v11 = x3[base + 8960 + 224];
  const size_t o = (size_t)r*224 + ch;
  const size_t SW = 2752512;
  xw[o]        = f2b(0.5f*(v00 + v01 + v10 + v11));   // cA
  xw[SW + o]   = f2b(0.5f*(v00 + v01 - v10 - v11));   // cH
  xw[2*SW + o] = f2b(0.5f*(v00 - v01 + v10 - v11));   // cV
  xw[3*SW + o] = f2b(0.5f*(v00 - v01 - v10 + v11));   // cD
}

/* ------------- window attention per (window, head) ------------- */
__global__ __launch_bounds__(256) void winattn_kernel(const float* __restrict__ qw, const float* __restrict__ kvw,
                                                      const float* __restrict__ pos, float* __restrict__ ow) {
  const int win = blockIdx.x >> 3, hd = blockIdx.x & 7;
  const int tid = threadIdx.x;
  __shared__ float qs[1792], ks[1792], vs[1792];
  __shared__ float sc[4096];
  for (int idx = tid; idx < 1792; idx += 256) {
    int tok = idx / 28, d = idx % 28;
    qs[idx] = qw [((size_t)(win*64+tok))*224 + hd*28 + d] * ATT_SCALE;
    ks[idx] = kvw[((size_t)(win*64+tok))*448 + hd*28 + d];
    vs[idx] = kvw[((size_t)(win*64+tok))*448 + 224 + hd*28 + d];
  }
  __syncthreads();
#pragma unroll
  for (int p = 0; p < 16; ++p) {
    int idx = tid + p*256;
    int i = idx >> 6, j = idx & 63;
    float a = 0.f;
#pragma unroll
    for (int d = 0; d < 28; ++d) a = fmaf(qs[i*28+d], ks[j*28+d], a);
    sc[idx] = a + pos[(hd*64 + i)*64 + j];
  }
  __syncthreads();
  if (tid < 64) {
    const int i = tid;
    float mx = -1e30f;
#pragma unroll
    for (int j = 0; j < 64; ++j) mx = fmaxf(mx, sc[i*64+j]);
    float s = 0.f;
#pragma unroll
    for (int j = 0; j < 64; ++j) { float e = expf(sc[i*64+j] - mx); sc[i*64+j] = e; s += e; }
    const float inv = 1.f / s;
#pragma unroll
    for (int j = 0; j < 64; ++j) sc[i*64+j] *= inv;
  }
  __syncthreads();
  for (int idx = tid; idx < 1792; idx += 256) {
    int i = idx / 28, d = idx % 28;
    float a = 0.f;
#pragma unroll
    for (int j = 0; j < 64; ++j) a = fmaf(sc[i*64+j], vs[j*28+d], a);
    ow[((size_t)(win*64+i))*224 + hd*28 + d] = a;
  }
}

/* ------------- un-window + bias, drop pad ------------- */
__global__ __launch_bounds__(256) void scatter_kernel(const float* __restrict__ proj, const float* __restrict__ bo,
                                                      float* __restrict__ wa) {
  const int gid = blockIdx.x*256 + threadIdx.x;
  const int ch = gid % 224; int r = gid / 224;
  const int tok = r % 64; const int win = r / 64;
  const int b = win / 6, rr = win % 6, wy = rr / 3, wx = rr % 3;
  const int ty = tok >> 3, tx = tok & 7;
  const int i = wy*8 + ty;
  const int jp = wx*8 + tx;
  if (jp < 20)
    wa[(((size_t)(b*16+i))*20 + jp)*224 + ch] = proj[gid] + bo[ch];
}

/* ------------- inverse Haar + final transpose to (b,h,w,c) f32 ------------- */
__global__ __launch_bounds__(256) void iwt_kernel(const float* __restrict__ wa, float* __restrict__ out) {
  const int gid = blockIdx.x*256 + threadIdx.x;
  const int ch = gid % 224; int r = gid / 224;
  const int j2 = r % 40; r /= 40;
  const int i2 = r % 32; const int b = r / 32;
  const size_t SB = 2293760;
  const size_t base = (((size_t)(b*16 + (i2>>1)))*20 + (j2>>1))*224 + ch;
  const float cA = wa[base];
  const float cH = wa[SB + base];
  const float cV = wa[2*SB + base];
  const float cD = wa[3*SB + base];
  const float sp = (i2 & 1) ? -1.f : 1.f;
  const float sq = (j2 & 1) ? -1.f : 1.f;
  out[gid] = 0.5f*(cA + sp*cH + sq*cV + sp*sq*cD);
}

/* =============================== launcher =============================== */
extern "C" void kernel_launch(void* const* d_in, const int* in_sizes, int n_in,
                              void* d_out, int out_size, void* d_ws, size_t ws_size,
                              hipStream_t stream) {
  (void)in_sizes; (void)n_in; (void)out_size; (void)ws_size;
  const float* x     = (const float*)d_in[0];
  const float* Wq    = (const float*)d_in[1];
  const float* Wkv   = (const float*)d_in[2];
  const float* lng   = (const float*)d_in[3];
  const float* lnb   = (const float*)d_in[4];
  const float* Wip   = (const float*)d_in[5];
  const float* convW = (const float*)d_in[6];
  const float* convB = (const float*)d_in[7];
  const float* xpW   = (const float*)d_in[8];
  const float* dtW   = (const float*)d_in[9];
  const float* dtB   = (const float*)d_in[10];
  const float* Alog  = (const float*)d_in[11];
  const float* Dp    = (const float*)d_in[12];
  const float* Wout  = (const float*)d_in[13];
  const float* skip  = (const float*)d_in[14];
  const float* Wp    = (const float*)d_in[15];
  const float* pbias = (const float*)d_in[16];
  const float* c3w   = (const float*)d_in[17];
  const float* c3b   = (const float*)d_in[18];
  const float* Wq1   = (const float*)d_in[19];
  const float* Wkv1  = (const float*)d_in[20];
  const float* pos   = (const float*)d_in[21];

  char* ws = (char*)d_ws;
  /* phased overlays; peak usage 191,176,704 bytes */
  float* x1    = (float*)(ws + 0);             // 36.7MB, later reused as wa (4 subband outputs)
  float* qbuf  = (float*)(ws + 36700160);      // phase A
  float* kvbuf = (float*)(ws + 73400320);      // phase A
  bf16*  xi    = (bf16*) (ws + 36700160);      // phase B (over qbuf)   [b][t][64]
  bf16*  xc    = (bf16*) (ws + 73400320);      // phase B (over kvbuf)  [b][t][64]
  bf16*  dts   = (bf16*) (ws + 110100480);     // [b][t][64]
  bf16*  Bcb   = (bf16*) (ws + 146800640);     // [b][t][16]
  bf16*  Ccb   = (bf16*) (ws + 155975680);     // [b][t][16]
  float* Pbuf  = (float*)(ws + 165150720);     // [b][chk][d][n]
  float* Fbuf  = (float*)(ws + 173539328);     // [b][chk][d][n]
  float* H0    = (float*)(ws + 181927936);     // [b][chk][d][n]
  bf16*  ybuf  = (bf16*) (ws + 36700160);      // over xi (dead)        [b][t][64]
  float* x3    = (float*)(ws + 36700160);      // over ybuf (dead)
  bf16*  xw    = (bf16*) (ws + 73400320);      // 4 subband windowed inputs
  float* qw    = (float*)(ws + 95420416);
  float* kvw   = (float*)(ws + 106430464);
  float* owb   = (float*)(ws + 128450560);
  float* projt = qw;                            // reuse qw after winattn
  float* wab   = (float*)(ws + 0);             // over x1 (dead after conv3d)
  float* nqs   = (float*)(ws + 190316544);
  float* nks   = (float*)(ws + 190345216);
  float* attnA = (float*)(ws + 190373888);

  /* -------- stage A: transposed cosine attention -------- */
  zero_kernel<<<56, 256, 0, stream>>>(nqs, 14336);
  gemm_kernel<float,float><<<dim3(4,640), 256, 0, stream>>>(x, Wq,  qbuf,  40960, 224, 224);
  gemm_kernel<float,float><<<dim3(7,640), 256, 0, stream>>>(x, Wkv, kvbuf, 40960, 448, 224);
  colnorm_kernel<<<512, 256, 0, stream>>>(qbuf, kvbuf, nqs, nks);
  gram_kernel<<<256, 256, 0, stream>>>(qbuf, kvbuf, nqs, nks, attnA);
  applyattn_kernel<<<dim3(256,143), 256, 0, stream>>>(attnA, kvbuf, x, x1);

  /* -------- stage B: LN + mamba + LN/proj residual -------- */
  mamba_in_kernel<<<dim3(35,32), 256, 0, stream>>>(x1, lng, lnb, Wip, xi);
  mamba_conv_kernel<<<dim3(35,32), 256, 0, stream>>>(xi, convW, convB, xpW, dtW, dtB, xc, dts, Bcb, Ccb);
  scan1_kernel<<<512, 256, 0, stream>>>(dts, xc, Bcb, Alog, Pbuf, Fbuf);
  scan2_kernel<<<128, 256, 0, stream>>>(Pbuf, Fbuf, H0);
  scan3_kernel<<<512, 256, 0, stream>>>(dts, xc, Bcb, Ccb, Alog, Dp, H0, ybuf);
  mamba_out_kernel<<<dim3(35,32), 256, 0, stream>>>(x1, ybuf, lng, lnb, Wip, Wout, skip, Wp, pbias);

  /* -------- stage C: 5x5x5 conv -------- */
  conv3d_kernel<<<35840, 256, 0, stream>>>(x1, c3w, c3b, x3);

  /* -------- stage D: DWT + 4x window attention + IWT -------- */
  dwtwin_kernel<<<10752, 256, 0, stream>>>(x3, xw);
  for (int s = 0; s < 4; ++s) {
    const float* Wo = (const float*)d_in[22 + 2*s];
    const float* bo = (const float*)d_in[23 + 2*s];
    const bf16* xws = xw + (size_t)s * 2752512;
    gemm_kernel<bf16,float><<<dim3(4,192), 256, 0, stream>>>(xws, Wq1,  qw,  12288, 224, 224);
    gemm_kernel<bf16,float><<<dim3(7,192), 256, 0, stream>>>(xws, Wkv1, kvw, 12288, 448, 224);
    winattn_kernel<<<1536, 256, 0, stream>>>(qw, kvw, pos, owb);
    gemm_kernel<float,float><<<dim3(4,192), 256, 0, stream>>>(owb, Wo, projt, 12288, 224, 224);
    scatter_kernel<<<10752, 256, 0, stream>>>(projt, bo, wab + (size_t)s * 2293760);
  }
  iwt_kernel<<<35840, 256, 0, stream>>>(wab, (float*)d_out);
}

// Round 4
// 2923.484 us; speedup vs baseline: 1.6359x; 1.6359x over previous
//
#include <hip/hip_runtime.h>
#include <hip/hip_bf16.h>
#include <math.h>

typedef __hip_bfloat16 bf16;

__device__ __forceinline__ float b2f(bf16 v){ return __bfloat162float(v); }
__device__ __forceinline__ bf16  f2b(float v){ return __float2bfloat16(v); }
__device__ __forceinline__ float cvt(float v){ return v; }
__device__ __forceinline__ float cvt(bf16 v){ return __bfloat162float(v); }
__device__ __forceinline__ float bfbits(unsigned u){ return __uint_as_float(u << 16); }
__device__ __forceinline__ unsigned short b2us(bf16 v){ union { bf16 b; unsigned short u; } c; c.b = v; return c.u; }
__device__ __forceinline__ void unpack8(uint4 q, float* f){
  f[0]=bfbits(q.x&0xffffu); f[1]=bfbits(q.x>>16);
  f[2]=bfbits(q.y&0xffffu); f[3]=bfbits(q.y>>16);
  f[4]=bfbits(q.z&0xffffu); f[5]=bfbits(q.z>>16);
  f[6]=bfbits(q.w&0xffffu); f[7]=bfbits(q.w>>16);
}
__device__ __forceinline__ uint4 pack8f(const float* f){
  uint4 q;
  q.x = (unsigned)b2us(f2b(f[0])) | ((unsigned)b2us(f2b(f[1]))<<16);
  q.y = (unsigned)b2us(f2b(f[2])) | ((unsigned)b2us(f2b(f[3]))<<16);
  q.z = (unsigned)b2us(f2b(f[4])) | ((unsigned)b2us(f2b(f[5]))<<16);
  q.w = (unsigned)b2us(f2b(f[6])) | ((unsigned)b2us(f2b(f[7]))<<16);
  return q;
}

#define NTOK 1280
#define LSEQ 8960
#define CHLEN 140
#define ATT_SCALE 0.1889822365046136f   /* 28^-0.5 */

/* ---------------- generic tiled GEMM: C(f32) = A @ B ---------------- */
template<typename TA, typename TB>
__global__ __launch_bounds__(256) void gemm_kernel(const TA* __restrict__ A, const TB* __restrict__ B,
                                                   float* __restrict__ C, int M, int N, int K) {
  __shared__ float As[16][64];
  __shared__ float Bs[16][64];
  const int tid = threadIdx.x;
  const int tx = tid & 15, ty = tid >> 4;
  const int m0 = blockIdx.y * 64, n0 = blockIdx.x * 64;
  const int ar = tid >> 4, ac = tid & 15;
  const int bn = tid & 63, bk = tid >> 6;
  float acc[4][4] = {};
  for (int k0 = 0; k0 < K; k0 += 16) {
#pragma unroll
    for (int s = 0; s < 4; ++s) {
      int m = m0 + ar + 16*s;
      float v = 0.f;
      if (m < M && (k0+ac) < K) v = cvt(A[(size_t)m*K + k0 + ac]);
      As[ac][ar + 16*s] = v;
    }
#pragma unroll
    for (int s = 0; s < 4; ++s) {
      int kk = bk + 4*s;
      float v = 0.f;
      if ((n0+bn) < N && (k0+kk) < K) v = cvt(B[(size_t)(k0+kk)*N + n0 + bn]);
      Bs[kk][bn] = v;
    }
    __syncthreads();
#pragma unroll
    for (int kk = 0; kk < 16; ++kk) {
      float a[4], b[4];
#pragma unroll
      for (int i = 0; i < 4; ++i) a[i] = As[kk][ty*4+i];
#pragma unroll
      for (int j = 0; j < 4; ++j) b[j] = Bs[kk][tx*4+j];
#pragma unroll
      for (int i = 0; i < 4; ++i)
#pragma unroll
        for (int j = 0; j < 4; ++j) acc[i][j] = fmaf(a[i], b[j], acc[i][j]);
    }
    __syncthreads();
  }
#pragma unroll
  for (int i = 0; i < 4; ++i) {
    int m = m0 + ty*4 + i;
    if (m >= M) continue;
#pragma unroll
    for (int j = 0; j < 4; ++j) {
      int n = n0 + tx*4 + j;
      if (n < N) C[(size_t)m*N + n] = acc[i][j];
    }
  }
}

__global__ __launch_bounds__(256) void zero_kernel(float* __restrict__ p, int n) {
  int i = blockIdx.x*256 + threadIdx.x;
  if (i < n) p[i] = 0.f;
}

/* ------------- stage A: column sum-of-squares for q (224) and k (first 224 of kv) ------------- */
__global__ __launch_bounds__(256) void colnorm_kernel(const float* __restrict__ qb, const float* __restrict__ kvb,
                                                      float* __restrict__ nqs, float* __restrict__ nks) {
  const int b  = blockIdx.x >> 4;
  const int nc = blockIdx.x & 15;
  const int tid = threadIdx.x;
  __shared__ float lq[224], lk[224];
  if (tid < 224) { lq[tid] = 0.f; lk[tid] = 0.f; }
  __syncthreads();
  const int n0 = nc * 80;
  for (int idx = tid; idx < 80*224; idx += 256) {
    int n = n0 + idx / 224, c = idx % 224;
    float v = qb[((size_t)(b*NTOK + n))*224 + c];
    atomicAdd(&lq[c], v*v);
    float w = kvb[((size_t)(b*NTOK + n))*448 + c];
    atomicAdd(&lk[c], w*w);
  }
  __syncthreads();
  if (tid < 224) {
    atomicAdd(&nqs[b*224 + tid], lq[tid]);
    atomicAdd(&nks[b*224 + tid], lk[tid]);
  }
}

/* ------------- stage A: 28x28 gram + softmax per (b, head) ------------- */
__global__ __launch_bounds__(256) void gram_kernel(const float* __restrict__ qb, const float* __restrict__ kvb,
                                                   const float* __restrict__ nqs, const float* __restrict__ nks,
                                                   float* __restrict__ attnA) {
  const int b = blockIdx.x >> 3, hd = blockIdx.x & 7;
  const int tid = threadIdx.x;
  __shared__ float kt[32][28];
  __shared__ float qt[32][28];
  __shared__ float sc[784];
  float acc[4] = {0.f,0.f,0.f,0.f};
  for (int nt = 0; nt < NTOK; nt += 32) {
    __syncthreads();
    for (int idx = tid; idx < 896; idx += 256) {
      int r = idx / 28, c = idx % 28;
      kt[r][c] = kvb[((size_t)(b*NTOK + nt + r))*448 + hd*28 + c];
      qt[r][c] = qb [((size_t)(b*NTOK + nt + r))*224 + hd*28 + c];
    }
    __syncthreads();
#pragma unroll
    for (int p = 0; p < 4; ++p) {
      int idx = tid + p*256;
      if (idx < 784) {
        int i = idx / 28, j = idx % 28;
        float s = 0.f;
#pragma unroll
        for (int r = 0; r < 32; ++r) s = fmaf(kt[r][i], qt[r][j], s);
        acc[p] += s;
      }
    }
  }
  __syncthreads();
#pragma unroll
  for (int p = 0; p < 4; ++p) {
    int idx = tid + p*256;
    if (idx < 784) {
      int i = idx / 28, j = idx % 28;
      float nk = fmaxf(sqrtf(nks[b*224 + hd*28 + i]), 1e-12f);
      float nq = fmaxf(sqrtf(nqs[b*224 + hd*28 + j]), 1e-12f);
      sc[idx] = acc[p] * ATT_SCALE / (nk * nq);
    }
  }
  __syncthreads();
  if (tid < 28) {
    int i = tid;
    float mx = -1e30f;
#pragma unroll
    for (int j = 0; j < 28; ++j) mx = fmaxf(mx, sc[i*28+j]);
    float e[28]; float s = 0.f;
#pragma unroll
    for (int j = 0; j < 28; ++j) { e[j] = expf(sc[i*28+j] - mx); s += e[j]; }
    float inv = 1.f / s;
#pragma unroll
    for (int j = 0; j < 28; ++j) attnA[(size_t)blockIdx.x*784 + i*28 + j] = e[j]*inv;
  }
}

/* ------------- stage A: apply attention over channels + residual ------------- */
__global__ __launch_bounds__(256) void applyattn_kernel(const float* __restrict__ attnA, const float* __restrict__ kvb,
                                                        const float* __restrict__ x, float* __restrict__ x1) {
  const int bhd = blockIdx.x;
  const int b = bhd >> 3, hd = bhd & 7;
  const int tid = threadIdx.x;
  __shared__ float a[784];
  for (int idx = tid; idx < 784; idx += 256) a[idx] = attnA[(size_t)bhd*784 + idx];
  __syncthreads();
  const int i = tid % 28;
  const int n = blockIdx.y * 9 + tid / 28;
  if (tid < 252 && n < NTOK) {
    const float* vrow = &kvb[((size_t)(b*NTOK + n))*448 + 224 + hd*28];
    float s = 0.f;
#pragma unroll
    for (int j = 0; j < 28; ++j) s = fmaf(a[i*28+j], vrow[j], s);
    size_t o = ((size_t)(b*NTOK + n))*224 + hd*28 + i;
    x1[o] = s + x[o];
  }
}

/* ------------- mamba: LN + in_proj (xi half) ----- xi time-major [b][t][64] ------------- */
__global__ __launch_bounds__(256) void mamba_in_kernel(const float* __restrict__ x1, const float* __restrict__ lng,
                                                       const float* __restrict__ lnb, const float* __restrict__ Wip,
                                                       bf16* __restrict__ xi) {
  __shared__ float W[2048];
  __shared__ float g[32], bb[32];
  const int tid = threadIdx.x;
  const int b = blockIdx.y;
  const int t = blockIdx.x*256 + tid;
  for (int idx = tid; idx < 2048; idx += 256) {
    int m = idx >> 6, d = idx & 63;
    W[idx] = Wip[m*128 + d];
  }
  if (tid < 32) { g[tid] = lng[tid]; bb[tid] = lnb[tid]; }
  __syncthreads();
  float xv[32];
  float mean = 0.f;
#pragma unroll
  for (int m = 0; m < 32; ++m) { xv[m] = x1[((size_t)(b*32+m))*LSEQ + t]; mean += xv[m]; }
  mean *= (1.f/32.f);
  float var = 0.f;
#pragma unroll
  for (int m = 0; m < 32; ++m) { float d = xv[m]-mean; var = fmaf(d, d, var); }
  var *= (1.f/32.f);
  const float rstd = rsqrtf(var + 1e-5f);
  float xn[32];
#pragma unroll
  for (int m = 0; m < 32; ++m) xn[m] = (xv[m]-mean)*rstd*g[m] + bb[m];
  bf16* row = xi + ((size_t)b*LSEQ + t)*64;
#pragma unroll
  for (int gi = 0; gi < 8; ++gi) {
    float sv[8];
#pragma unroll
    for (int j = 0; j < 8; ++j) {
      int d = gi*8 + j;
      float s = 0.f;
#pragma unroll
      for (int m = 0; m < 32; ++m) s = fmaf(xn[m], W[m*64+d], s);
      sv[j] = s;
    }
    *(uint4*)(row + gi*8) = pack8f(sv);
  }
}

/* ------------- mamba: conv + silu + x_proj + dt --- LDS-tiled, 64 t per block ------------- */
__global__ __launch_bounds__(256) void mamba_conv_kernel(const bf16* __restrict__ xi, const float* __restrict__ convW,
    const float* __restrict__ convB, const float* __restrict__ xpW, const float* __restrict__ dtW,
    const float* __restrict__ dtB, bf16* __restrict__ xc, bf16* __restrict__ dts,
    bf16* __restrict__ Bc, bf16* __restrict__ Ccs) {
  __shared__ float xit[67][65];    // xi rows t0-3 .. t0+63, padded
  __shared__ float xct[64][65];    // conv+silu result, padded
  __shared__ float xdbl[64][36];   // x_dbl (34 cols), padded to 36
  __shared__ float Wc[256], bcs[64], Wxp[2176], Wdt[128], bdt[64];
  const int tid = threadIdx.x;
  const int b = blockIdx.y;
  const int t0 = blockIdx.x * 64;

  if (tid < 256) Wc[tid] = convW[tid];
  for (int idx = tid; idx < 2176; idx += 256) Wxp[idx] = xpW[idx];
  if (tid < 128) Wdt[tid] = dtW[tid];
  if (tid < 64) { bcs[tid] = convB[tid]; bdt[tid] = dtB[tid]; }
  /* phase 0: stage xi tile (67 rows x 64 ch) */
  for (int idx = tid; idx < 67*8; idx += 256) {
    const int row = idx >> 3, seg = idx & 7;
    const int gt = t0 + row - 3;
    float f[8];
    if (gt >= 0) {
      uint4 q = *(const uint4*)(xi + ((size_t)b*LSEQ + gt)*64 + seg*8);
      unpack8(q, f);
    } else {
#pragma unroll
      for (int j = 0; j < 8; ++j) f[j] = 0.f;
    }
#pragma unroll
    for (int j = 0; j < 8; ++j) xit[row][seg*8 + j] = f[j];
  }
  __syncthreads();

  /* phase 1: conv + silu, write xct + global xc */
  {
    const int tl = tid >> 2, cg = tid & 3;
    float sv[16];
#pragma unroll
    for (int j = 0; j < 16; ++j) {
      const int d = cg*16 + j;
      float s = bcs[d];
      s = fmaf(xit[tl+0][d], Wc[d*4+0], s);
      s = fmaf(xit[tl+1][d], Wc[d*4+1], s);
      s = fmaf(xit[tl+2][d], Wc[d*4+2], s);
      s = fmaf(xit[tl+3][d], Wc[d*4+3], s);
      s = s / (1.f + expf(-s));
      xct[tl][d] = s;
      sv[j] = s;
    }
    bf16* out = xc + ((size_t)b*LSEQ + t0 + tl)*64 + cg*16;
    *(uint4*)(out)     = pack8f(sv);
    *(uint4*)(out + 8) = pack8f(sv + 8);
  }
  __syncthreads();

  /* phase 2: x_dbl = xc @ Wxp  (64 t x 34 n) */
  {
    const int tl = tid & 63, g = tid >> 6;
    for (int n = g; n < 34; n += 4) {
      float s = 0.f;
#pragma unroll
      for (int d = 0; d < 64; ++d) s = fmaf(xct[tl][d], Wxp[d*34 + n], s);
      xdbl[tl][n] = s;
    }
  }
  __syncthreads();

  /* phase 3a: pack B/C rows */
  if (tid < 256) {
    const int which = tid >> 7;          // 0 = Bc, 1 = Cc
    const int idx = tid & 127;
    const int tl = idx >> 1, half = idx & 1;
    const float* src = &xdbl[tl][2 + which*16 + half*8];
    bf16* dst = (which ? Ccs : Bc) + ((size_t)b*LSEQ + t0 + tl)*16 + half*8;
    *(uint4*)dst = pack8f(src);
  }
  /* phase 3b: dt = softplus(x_dbl[:, :2] @ dtW + bias) */
  {
    const int tl = tid >> 2, cg = tid & 3;
    const float x0 = xdbl[tl][0], x1v = xdbl[tl][1];
    float sv[16];
#pragma unroll
    for (int j = 0; j < 16; ++j) {
      const int d = cg*16 + j;
      float v = fmaf(x0, Wdt[d], fmaf(x1v, Wdt[64+d], bdt[d]));
      v = (v > 20.f) ? v : log1pf(expf(v));
      sv[j] = v;
    }
    bf16* out = dts + ((size_t)b*LSEQ + t0 + tl)*64 + cg*16;
    *(uint4*)(out)     = pack8f(sv);
    *(uint4*)(out + 8) = pack8f(sv + 8);
  }
}

/* ------------- scan pass 1: per-chunk decay product + local final (lane = d) ------------- */
__global__ __launch_bounds__(256) void scan1_kernel(const bf16* __restrict__ dts, const bf16* __restrict__ xc,
    const bf16* __restrict__ Bc, const float* __restrict__ Alog, float* __restrict__ P, float* __restrict__ F) {
  const int w = blockIdx.x*4 + (threadIdx.x >> 6);
  const int d = threadIdx.x & 63;
  const int b = w >> 6, chk = w & 63;
  float A[16];
#pragma unroll
  for (int n = 0; n < 16; ++n) A[n] = -expf(Alog[d*16+n]);
  float Pr[16], Fr[16];
#pragma unroll
  for (int n = 0; n < 16; ++n) { Pr[n] = 1.f; Fr[n] = 0.f; }
  const size_t tbase = (size_t)b*LSEQ + (size_t)chk*CHLEN;
  for (int i = 0; i < CHLEN; ++i) {
    const size_t t = tbase + i;
    float dtv = b2f(dts[t*64 + d]);
    float u   = b2f(xc [t*64 + d]);
    float du  = dtv*u;
    const uint4* bp = (const uint4*)(Bc + t*16);
    float Bv[16]; unpack8(bp[0], Bv); unpack8(bp[1], Bv+8);
#pragma unroll
    for (int n = 0; n < 16; ++n) {
      float a = expf(dtv*A[n]);
      Pr[n] *= a;
      Fr[n] = fmaf(a, Fr[n], du*Bv[n]);
    }
  }
  const size_t o = (((size_t)(b*64 + chk))*64 + d)*16;
  float4* Pp = (float4*)(P + o);
  float4* Fp = (float4*)(F + o);
#pragma unroll
  for (int q = 0; q < 4; ++q) {
    Pp[q] = make_float4(Pr[4*q], Pr[4*q+1], Pr[4*q+2], Pr[4*q+3]);
    Fp[q] = make_float4(Fr[4*q], Fr[4*q+1], Fr[4*q+2], Fr[4*q+3]);
  }
}

/* ------------- scan pass 2: sequential combine across chunks ------------- */
__global__ __launch_bounds__(256) void scan2_kernel(const float* __restrict__ P, const float* __restrict__ F,
                                                    float* __restrict__ H0) {
  const int idx = blockIdx.x*256 + threadIdx.x;   // 32768 = 32 b x 64 d x 16 n
  const int b = idx >> 10, dn = idx & 1023;
  const size_t base = (size_t)b*64*1024 + dn;
  float h = 0.f;
  for (int ch = 0; ch < 64; ++ch) {
    const size_t a = base + (size_t)ch*1024;
    H0[a] = h;
    h = fmaf(P[a], h, F[a]);
  }
}

/* ------------- scan pass 3: replay with correct init, emit y (+ u*Dp), lane = d ------------- */
__global__ __launch_bounds__(256) void scan3_kernel(const bf16* __restrict__ dts, const bf16* __restrict__ xc,
    const bf16* __restrict__ Bc, const bf16* __restrict__ Ccs, const float* __restrict__ Alog,
    const float* __restrict__ Dp, const float* __restrict__ H0, bf16* __restrict__ y) {
  const int w = blockIdx.x*4 + (threadIdx.x >> 6);
  const int d = threadIdx.x & 63;
  const int b = w >> 6, chk = w & 63;
  float A[16];
#pragma unroll
  for (int n = 0; n < 16; ++n) A[n] = -expf(Alog[d*16+n]);
  float h[16];
  const size_t hb = (((size_t)(b*64 + chk))*64 + d)*16;
  const float4* Hp = (const float4*)(H0 + hb);
#pragma unroll
  for (int q = 0; q < 4; ++q) {
    float4 v = Hp[q];
    h[4*q] = v.x; h[4*q+1] = v.y; h[4*q+2] = v.z; h[4*q+3] = v.w;
  }
  const float Dpd = Dp[d];
  const size_t tbase = (size_t)b*LSEQ + (size_t)chk*CHLEN;
  for (int i = 0; i < CHLEN; ++i) {
    const size_t t = tbase + i;
    float dtv = b2f(dts[t*64 + d]);
    float u   = b2f(xc [t*64 + d]);
    float du  = dtv*u;
    const uint4* bp = (const uint4*)(Bc  + t*16);
    const uint4* cp = (const uint4*)(Ccs + t*16);
    float Bv[16], Cv[16];
    unpack8(bp[0], Bv); unpack8(bp[1], Bv+8);
    unpack8(cp[0], Cv); unpack8(cp[1], Cv+8);
    float yv = 0.f;
#pragma unroll
    for (int n = 0; n < 16; ++n) {
      float a = expf(dtv*A[n]);
      h[n] = fmaf(a, h[n], du*Bv[n]);
      yv = fmaf(h[n], Cv[n], yv);
    }
    y[t*64 + d] = f2b(yv + u*Dpd);
  }
}

/* ------------- mamba tail: gate, out_proj, skip, LN, proj, residual (x1 in place) ------------- */
__global__ __launch_bounds__(256) void mamba_out_kernel(float* __restrict__ x1, const bf16* __restrict__ y,
    const float* __restrict__ lng, const float* __restrict__ lnb, const float* __restrict__ Wip,
    const float* __restrict__ Wout, const float* __restrict__ skipp, const float* __restrict__ Wp,
    const float* __restrict__ pbias) {
  __shared__ float Wz[2048];   // in_proj z-half, [m][d]
  __shared__ float Wo[2048];   // out_proj, [d][m]
  __shared__ float Pw[1024];   // proj_W, [m][m2]
  __shared__ float g[32], bb[32], pb[32];
  __shared__ float sskip;
  const int tid = threadIdx.x;
  for (int idx = tid; idx < 2048; idx += 256) {
    int m = idx >> 6, d = idx & 63;
    Wz[m*64+d] = Wip[m*128 + 64 + d];
  }
  for (int idx = tid; idx < 2048; idx += 256) Wo[idx] = Wout[idx];
  for (int idx = tid; idx < 1024; idx += 256) Pw[idx] = Wp[idx];
  if (tid < 32) { g[tid] = lng[tid]; bb[tid] = lnb[tid]; pb[tid] = pbias[tid]; }
  if (tid == 0) sskip = skipp[0];
  __syncthreads();
  const int b = blockIdx.y;
  const int t = blockIdx.x*256 + tid;
  float xv[32];
  float mean = 0.f;
#pragma unroll
  for (int m = 0; m < 32; ++m) { xv[m] = x1[((size_t)(b*32+m))*LSEQ + t]; mean += xv[m]; }
  mean *= (1.f/32.f);
  float var = 0.f;
#pragma unroll
  for (int m = 0; m < 32; ++m) { float d = xv[m]-mean; var = fmaf(d, d, var); }
  var *= (1.f/32.f);
  const float rstd = rsqrtf(var + 1e-5f);
  float xn[32];
#pragma unroll
  for (int m = 0; m < 32; ++m) xn[m] = (xv[m]-mean)*rstd*g[m] + bb[m];
  float out[32] = {};
  const bf16* yrow = y + ((size_t)b*LSEQ + t)*64;
#pragma unroll
  for (int gi = 0; gi < 8; ++gi) {
    uint4 q = *(const uint4*)(yrow + gi*8);
    float yv8[8]; unpack8(q, yv8);
#pragma unroll
    for (int j = 0; j < 8; ++j) {
      int d = gi*8 + j;
      float zd = 0.f;
#pragma unroll
      for (int m = 0; m < 32; ++m) zd = fmaf(xn[m], Wz[m*64+d], zd);
      float gd = yv8[j] * zd / (1.f + expf(-zd));
#pragma unroll
      for (int m = 0; m < 32; ++m) out[m] = fmaf(gd, Wo[d*32+m], out[m]);
    }
  }
#pragma unroll
  for (int m = 0; m < 32; ++m) out[m] = fmaf(sskip, xn[m], out[m]);
  float mean2 = 0.f;
#pragma unroll
  for (int m = 0; m < 32; ++m) mean2 += out[m];
  mean2 *= (1.f/32.f);
  float var2 = 0.f;
#pragma unroll
  for (int m = 0; m < 32; ++m) { float d = out[m]-mean2; var2 = fmaf(d, d, var2); }
  var2 *= (1.f/32.f);
  const float rstd2 = rsqrtf(var2 + 1e-5f);
#pragma unroll
  for (int m = 0; m < 32; ++m) out[m] = (out[m]-mean2)*rstd2*g[m] + bb[m];
  for (int m2 = 0; m2 < 32; ++m2) {
    float r = pb[m2];
#pragma unroll
    for (int m = 0; m < 32; ++m) r = fmaf(out[m], Pw[m*32+m2], r);
    x1[((size_t)(b*32+m2))*LSEQ + t] = r + xv[m2];
  }
}

/* ------------- 5x5x5 conv over (h,w,c), single channel ------------- */
__global__ __launch_bounds__(256) void conv3d_kernel(const float* __restrict__ x2, const float* __restrict__ w,
                                                     const float* __restrict__ bias, float* __restrict__ x3) {
  __shared__ float ww[125];
  __shared__ float b0;
  const int tid = threadIdx.x;
  if (tid < 125) ww[tid] = w[tid];
  if (tid == 0) b0 = bias[0];
  __syncthreads();
  const int gid = blockIdx.x*256 + tid;
  int k = gid % 224; int r = gid / 224;
  int j = r % 40; r /= 40;
  int i = r % 32; int b = r / 32;
  float acc = 0.f;
  for (int di = 0; di < 5; ++di) {
    int ii = i + di - 2; if (ii < 0 || ii >= 32) continue;
    for (int dj = 0; dj < 5; ++dj) {
      int jj = j + dj - 2; if (jj < 0 || jj >= 40) continue;
      const float* row = &x2[(((size_t)(b*32+ii))*40 + jj)*224];
      const float* wr = &ww[(di*5+dj)*5];
#pragma unroll
      for (int dk = 0; dk < 5; ++dk) {
        int kk = k + dk - 2;
        if (kk >= 0 && kk < 224) acc = fmaf(wr[dk], row[kk], acc);
      }
    }
  }
  x3[gid] = acc + b0;
}

/* ------------- DWT + reflect-pad + window partition (all 4 subbands at once) ------------- */
__global__ __launch_bounds__(256) void dwtwin_kernel(const float* __restrict__ x3, bf16* __restrict__ xw) {
  const int gid = blockIdx.x*256 + threadIdx.x;   // < 192*64*224
  const int ch = gid % 224; int r = gid / 224;
  const int tok = r % 64; const int win = r / 64;
  const int b = win / 6, rr = win % 6, wy = rr / 3, wx = rr % 3;
  const int ty = tok >> 3, tx = tok & 7;
  const int i = wy*8 + ty;
  const int jp = wx*8 + tx;
  const int j = (jp < 20) ? jp : (38 - jp);   // reflect pad on the right
  const size_t base = (((size_t)(b*32 + 2*i))*40 + 2*j)*224 + ch;
  const float v00 = x3[base];
  const float v01 = x3[base + 224];
  const float v10 = x3[base + 8960];
  const float v11 = x3[base + 8960 + 224];
  const size_t o = (size_t)r*224 + ch;
  const size_t SW = 2752512;
  xw[o]        = f2b(0.5f*(v00 + v01 + v10 + v11));   // cA
  xw[SW + o]   = f2b(0.5f*(v00 + v01 - v10 - v11));   // cH
  xw[2*SW + o] = f2b(0.5f*(v00 - v01 + v10 - v11));   // cV
  xw[3*SW + o] = f2b(0.5f*(v00 - v01 - v10 + v11));   // cD
}

/* ------------- window attention per (window, head) ------------- */
__global__ __launch_bounds__(256) void winattn_kernel(const float* __restrict__ qw, const float* __restrict__ kvw,
                                                      const float* __restrict__ pos, float* __restrict__ ow) {
  const int win = blockIdx.x >> 3, hd = blockIdx.x & 7;
  const int tid = threadIdx.x;
  __shared__ float qs[1792], ks[1792], vs[1792];
  __shared__ float sc[4096];
  for (int idx = tid; idx < 1792; idx += 256) {
    int tok = idx / 28, d = idx % 28;
    qs[idx] = qw [((size_t)(win*64+tok))*224 + hd*28 + d] * ATT_SCALE;
    ks[idx] = kvw[((size_t)(win*64+tok))*448 + hd*28 + d];
    vs[idx] = kvw[((size_t)(win*64+tok))*448 + 224 + hd*28 + d];
  }
  __syncthreads();
#pragma unroll
  for (int p = 0; p < 16; ++p) {
    int idx = tid + p*256;
    int i = idx >> 6, j = idx & 63;
    float a = 0.f;
#pragma unroll
    for (int d = 0; d < 28; ++d) a = fmaf(qs[i*28+d], ks[j*28+d], a);
    sc[idx] = a + pos[(hd*64 + i)*64 + j];
  }
  __syncthreads();
  if (tid < 64) {
    const int i = tid;
    float mx = -1e30f;
#pragma unroll
    for (int j = 0; j < 64; ++j) mx = fmaxf(mx, sc[i*64+j]);
    float s = 0.f;
#pragma unroll
    for (int j = 0; j < 64; ++j) { float e = expf(sc[i*64+j] - mx); sc[i*64+j] = e; s += e; }
    const float inv = 1.f / s;
#pragma unroll
    for (int j = 0; j < 64; ++j) sc[i*64+j] *= inv;
  }
  __syncthreads();
  for (int idx = tid; idx < 1792; idx += 256) {
    int i = idx / 28, d = idx % 28;
    float a = 0.f;
#pragma unroll
    for (int j = 0; j < 64; ++j) a = fmaf(sc[i*64+j], vs[j*28+d], a);
    ow[((size_t)(win*64+i))*224 + hd*28 + d] = a;
  }
}

/* ------------- un-window + bias, drop pad ------------- */
__global__ __launch_bounds__(256) void scatter_kernel(const float* __restrict__ proj, const float* __restrict__ bo,
                                                      float* __restrict__ wa) {
  const int gid = blockIdx.x*256 + threadIdx.x;
  const int ch = gid % 224; int r = gid / 224;
  const int tok = r % 64; const int win = r / 64;
  const int b = win / 6, rr = win % 6, wy = rr / 3, wx = rr % 3;
  const int ty = tok >> 3, tx = tok & 7;
  const int i = wy*8 + ty;
  const int jp = wx*8 + tx;
  if (jp < 20)
    wa[(((size_t)(b*16+i))*20 + jp)*224 + ch] = proj[gid] + bo[ch];
}

/* ------------- inverse Haar + final transpose to (b,h,w,c) f32 ------------- */
__global__ __launch_bounds__(256) void iwt_kernel(const float* __restrict__ wa, float* __restrict__ out) {
  const int gid = blockIdx.x*256 + threadIdx.x;
  const int ch = gid % 224; int r = gid / 224;
  const int j2 = r % 40; r /= 40;
  const int i2 = r % 32; const int b = r / 32;
  const size_t SB = 2293760;
  const size_t base = (((size_t)(b*16 + (i2>>1)))*20 + (j2>>1))*224 + ch;
  const float cA = wa[base];
  const float cH = wa[SB + base];
  const float cV = wa[2*SB + base];
  const float cD = wa[3*SB + base];
  const float sp = (i2 & 1) ? -1.f : 1.f;
  const float sq = (j2 & 1) ? -1.f : 1.f;
  out[gid] = 0.5f*(cA + sp*cH + sq*cV + sp*sq*cD);
}

/* =============================== launcher =============================== */
extern "C" void kernel_launch(void* const* d_in, const int* in_sizes, int n_in,
                              void* d_out, int out_size, void* d_ws, size_t ws_size,
                              hipStream_t stream) {
  (void)in_sizes; (void)n_in; (void)out_size; (void)ws_size;
  const float* x     = (const float*)d_in[0];
  const float* Wq    = (const float*)d_in[1];
  const float* Wkv   = (const float*)d_in[2];
  const float* lng   = (const float*)d_in[3];
  const float* lnb   = (const float*)d_in[4];
  const float* Wip   = (const float*)d_in[5];
  const float* convW = (const float*)d_in[6];
  const float* convB = (const float*)d_in[7];
  const float* xpW   = (const float*)d_in[8];
  const float* dtW   = (const float*)d_in[9];
  const float* dtB   = (const float*)d_in[10];
  const float* Alog  = (const float*)d_in[11];
  const float* Dp    = (const float*)d_in[12];
  const float* Wout  = (const float*)d_in[13];
  const float* skip  = (const float*)d_in[14];
  const float* Wp    = (const float*)d_in[15];
  const float* pbias = (const float*)d_in[16];
  const float* c3w   = (const float*)d_in[17];
  const float* c3b   = (const float*)d_in[18];
  const float* Wq1   = (const float*)d_in[19];
  const float* Wkv1  = (const float*)d_in[20];
  const float* pos   = (const float*)d_in[21];

  char* ws = (char*)d_ws;
  /* phased overlays; peak usage 191,176,704 bytes */
  float* x1    = (float*)(ws + 0);             // 36.7MB, later reused as wa (4 subband outputs)
  float* qbuf  = (float*)(ws + 36700160);      // phase A
  float* kvbuf = (float*)(ws + 73400320);      // phase A
  bf16*  xi    = (bf16*) (ws + 36700160);      // phase B (over qbuf)   [b][t][64]
  bf16*  xc    = (bf16*) (ws + 73400320);      // phase B (over kvbuf)  [b][t][64]
  bf16*  dts   = (bf16*) (ws + 110100480);     // [b][t][64]
  bf16*  Bcb   = (bf16*) (ws + 146800640);     // [b][t][16]
  bf16*  Ccb   = (bf16*) (ws + 155975680);     // [b][t][16]
  float* Pbuf  = (float*)(ws + 165150720);     // [b][chk][d][n]
  float* Fbuf  = (float*)(ws + 173539328);     // [b][chk][d][n]
  float* H0    = (float*)(ws + 181927936);     // [b][chk][d][n]
  bf16*  ybuf  = (bf16*) (ws + 36700160);      // over xi (dead)        [b][t][64]
  float* x3    = (float*)(ws + 36700160);      // over ybuf (dead)
  bf16*  xw    = (bf16*) (ws + 73400320);      // 4 subband windowed inputs
  float* qw    = (float*)(ws + 95420416);
  float* kvw   = (float*)(ws + 106430464);
  float* owb   = (float*)(ws + 128450560);
  float* projt = qw;                            // reuse qw after winattn
  float* wab   = (float*)(ws + 0);             // over x1 (dead after conv3d)
  float* nqs   = (float*)(ws + 190316544);
  float* nks   = (float*)(ws + 190345216);
  float* attnA = (float*)(ws + 190373888);

  /* -------- stage A: transposed cosine attention -------- */
  zero_kernel<<<56, 256, 0, stream>>>(nqs, 14336);
  gemm_kernel<float,float><<<dim3(4,640), 256, 0, stream>>>(x, Wq,  qbuf,  40960, 224, 224);
  gemm_kernel<float,float><<<dim3(7,640), 256, 0, stream>>>(x, Wkv, kvbuf, 40960, 448, 224);
  colnorm_kernel<<<512, 256, 0, stream>>>(qbuf, kvbuf, nqs, nks);
  gram_kernel<<<256, 256, 0, stream>>>(qbuf, kvbuf, nqs, nks, attnA);
  applyattn_kernel<<<dim3(256,143), 256, 0, stream>>>(attnA, kvbuf, x, x1);

  /* -------- stage B: LN + mamba + LN/proj residual -------- */
  mamba_in_kernel<<<dim3(35,32), 256, 0, stream>>>(x1, lng, lnb, Wip, xi);
  mamba_conv_kernel<<<dim3(140,32), 256, 0, stream>>>(xi, convW, convB, xpW, dtW, dtB, xc, dts, Bcb, Ccb);
  scan1_kernel<<<512, 256, 0, stream>>>(dts, xc, Bcb, Alog, Pbuf, Fbuf);
  scan2_kernel<<<128, 256, 0, stream>>>(Pbuf, Fbuf, H0);
  scan3_kernel<<<512, 256, 0, stream>>>(dts, xc, Bcb, Ccb, Alog, Dp, H0, ybuf);
  mamba_out_kernel<<<dim3(35,32), 256, 0, stream>>>(x1, ybuf, lng, lnb, Wip, Wout, skip, Wp, pbias);

  /* -------- stage C: 5x5x5 conv -------- */
  conv3d_kernel<<<35840, 256, 0, stream>>>(x1, c3w, c3b, x3);

  /* -------- stage D: DWT + 4x window attention + IWT -------- */
  dwtwin_kernel<<<10752, 256, 0, stream>>>(x3, xw);
  for (int s = 0; s < 4; ++s) {
    const float* Wo = (const float*)d_in[22 + 2*s];
    const float* bo = (const float*)d_in[23 + 2*s];
    const bf16* xws = xw + (size_t)s * 2752512;
    gemm_kernel<bf16,float><<<dim3(4,192), 256, 0, stream>>>(xws, Wq1,  qw,  12288, 224, 224);
    gemm_kernel<bf16,float><<<dim3(7,192), 256, 0, stream>>>(xws, Wkv1, kvw, 12288, 448, 224);
    winattn_kernel<<<1536, 256, 0, stream>>>(qw, kvw, pos, owb);
    gemm_kernel<float,float><<<dim3(4,192), 256, 0, stream>>>(owb, Wo, projt, 12288, 224, 224);
    scatter_kernel<<<10752, 256, 0, stream>>>(projt, bo, wab + (size_t)s * 2293760);
  }
  iwt_kernel<<<35840, 256, 0, stream>>>(wab, (float*)d_out);
}

// Round 5
// 1974.400 us; speedup vs baseline: 2.4223x; 1.4807x over previous
//
#include <hip/hip_runtime.h>
#include <hip/hip_bf16.h>
#include <math.h>

typedef __hip_bfloat16 bf16;
typedef __attribute__((ext_vector_type(8))) short bf16x8;
typedef __attribute__((ext_vector_type(4))) float f32x4;

__device__ __forceinline__ float b2f(bf16 v){ return __bfloat162float(v); }
__device__ __forceinline__ bf16  f2b(float v){ return __float2bfloat16(v); }
__device__ __forceinline__ float bfbits(unsigned u){ return __uint_as_float(u << 16); }
__device__ __forceinline__ unsigned short b2us(bf16 v){ union { bf16 b; unsigned short u; } c; c.b = v; return c.u; }
__device__ __forceinline__ void unpack8(uint4 q, float* f){
  f[0]=bfbits(q.x&0xffffu); f[1]=bfbits(q.x>>16);
  f[2]=bfbits(q.y&0xffffu); f[3]=bfbits(q.y>>16);
  f[4]=bfbits(q.z&0xffffu); f[5]=bfbits(q.z>>16);
  f[6]=bfbits(q.w&0xffffu); f[7]=bfbits(q.w>>16);
}
__device__ __forceinline__ uint4 pack8f(const float* f){
  uint4 q;
  q.x = (unsigned)b2us(f2b(f[0])) | ((unsigned)b2us(f2b(f[1]))<<16);
  q.y = (unsigned)b2us(f2b(f[2])) | ((unsigned)b2us(f2b(f[3]))<<16);
  q.z = (unsigned)b2us(f2b(f[4])) | ((unsigned)b2us(f2b(f[5]))<<16);
  q.w = (unsigned)b2us(f2b(f[6])) | ((unsigned)b2us(f2b(f[7]))<<16);
  return q;
}

#define NTOK 1280
#define LSEQ 8960
#define CHLEN 140
#define ATT_SCALE 0.1889822365046136f   /* 28^-0.5 */

/* ---------------- fp32 -> bf16 convert (8 elems/thread) ---------------- */
__global__ __launch_bounds__(256) void cvt_bf16_kernel(const float* __restrict__ src, bf16* __restrict__ dst, int n8) {
  int i = blockIdx.x*256 + threadIdx.x;
  if (i >= n8) return;
  const float4* s = (const float4*)(src + (size_t)i*8);
  float4 a = s[0], b = s[1];
  float f[8] = {a.x,a.y,a.z,a.w,b.x,b.y,b.z,b.w};
  *(uint4*)(dst + (size_t)i*8) = pack8f(f);
}

/* ---------------- W[K][N] fp32 -> Wt[N][K] bf16 ---------------- */
__global__ __launch_bounds__(256) void transpose_bf16_kernel(const float* __restrict__ W, bf16* __restrict__ Wt,
                                                             int K, int N) {
  int idx = blockIdx.x*256 + threadIdx.x;
  if (idx >= N*K) return;
  int n = idx / K, k = idx % K;
  Wt[idx] = f2b(W[(size_t)k*N + n]);
}

/* ---------------- MFMA GEMM: C(f32)[M][N] = A(bf16)[M][K] @ Bt(bf16)[N][K]^T ----------------
   tile 64x64, 256 thr = 4 waves; wave w -> rows [64*by+16w, +16); 4 n-subtiles of 16.
   Requires: M % 64 == 0, K % 32 == 0. N guarded. */
__global__ __launch_bounds__(256) void mfma_gemm_kernel(const bf16* __restrict__ A, const bf16* __restrict__ Bt,
                                                        float* __restrict__ C, int M, int N, int K) {
  __shared__ short As[64][40];
  __shared__ short Bs[64][40];
  const int tid = threadIdx.x;
  const int wave = tid >> 6, lane = tid & 63;
  const int m0 = blockIdx.y*64, n0 = blockIdx.x*64;
  const int lrow = tid >> 2, lseg = (tid & 3) * 8;
  const int mrow = wave*16 + (lane & 15);
  const int kq = (lane >> 4) * 8;
  f32x4 acc[4] = {};
  for (int k0 = 0; k0 < K; k0 += 32) {
    uint4 av = *(const uint4*)(A + (size_t)(m0+lrow)*K + k0 + lseg);
    uint4 bv = make_uint4(0u,0u,0u,0u);
    if (n0 + lrow < N) bv = *(const uint4*)(Bt + (size_t)(n0+lrow)*K + k0 + lseg);
    __syncthreads();
    *(uint4*)&As[lrow][lseg] = av;
    *(uint4*)&Bs[lrow][lseg] = bv;
    __syncthreads();
    bf16x8 af = *(const bf16x8*)&As[mrow][kq];
#pragma unroll
    for (int nt = 0; nt < 4; ++nt) {
      bf16x8 bfv = *(const bf16x8*)&Bs[nt*16 + (lane & 15)][kq];
      acc[nt] = __builtin_amdgcn_mfma_f32_16x16x32_bf16(af, bfv, acc[nt], 0, 0, 0);
    }
  }
  const int quad = lane >> 4, col = lane & 15;
#pragma unroll
  for (int nt = 0; nt < 4; ++nt) {
    int n = n0 + nt*16 + col;
    if (n >= N) continue;
#pragma unroll
    for (int r = 0; r < 4; ++r) {
      int m = m0 + wave*16 + quad*4 + r;
      C[(size_t)m*N + n] = acc[nt][r];
    }
  }
}

__global__ __launch_bounds__(256) void zero_kernel(float* __restrict__ p, int n) {
  int i = blockIdx.x*256 + threadIdx.x;
  if (i < n) p[i] = 0.f;
}

/* ------------- stage A: column sum-of-squares for q (224) and k (first 224 of kv) ------------- */
__global__ __launch_bounds__(256) void colnorm_kernel(const float* __restrict__ qb, const float* __restrict__ kvb,
                                                      float* __restrict__ nqs, float* __restrict__ nks) {
  const int b  = blockIdx.x >> 4;
  const int nc = blockIdx.x & 15;
  const int tid = threadIdx.x;
  __shared__ float lq[224], lk[224];
  if (tid < 224) { lq[tid] = 0.f; lk[tid] = 0.f; }
  __syncthreads();
  const int n0 = nc * 80;
  for (int idx = tid; idx < 80*224; idx += 256) {
    int n = n0 + idx / 224, c = idx % 224;
    float v = qb[((size_t)(b*NTOK + n))*224 + c];
    atomicAdd(&lq[c], v*v);
    float w = kvb[((size_t)(b*NTOK + n))*448 + c];
    atomicAdd(&lk[c], w*w);
  }
  __syncthreads();
  if (tid < 224) {
    atomicAdd(&nqs[b*224 + tid], lq[tid]);
    atomicAdd(&nks[b*224 + tid], lk[tid]);
  }
}

/* ------------- stage A: 28x28 gram + softmax per (b, head) ------------- */
__global__ __launch_bounds__(256) void gram_kernel(const float* __restrict__ qb, const float* __restrict__ kvb,
                                                   const float* __restrict__ nqs, const float* __restrict__ nks,
                                                   float* __restrict__ attnA) {
  const int b = blockIdx.x >> 3, hd = blockIdx.x & 7;
  const int tid = threadIdx.x;
  __shared__ float kt[32][28];
  __shared__ float qt[32][28];
  __shared__ float sc[784];
  float acc[4] = {0.f,0.f,0.f,0.f};
  for (int nt = 0; nt < NTOK; nt += 32) {
    __syncthreads();
    for (int idx = tid; idx < 896; idx += 256) {
      int r = idx / 28, c = idx % 28;
      kt[r][c] = kvb[((size_t)(b*NTOK + nt + r))*448 + hd*28 + c];
      qt[r][c] = qb [((size_t)(b*NTOK + nt + r))*224 + hd*28 + c];
    }
    __syncthreads();
#pragma unroll
    for (int p = 0; p < 4; ++p) {
      int idx = tid + p*256;
      if (idx < 784) {
        int i = idx / 28, j = idx % 28;
        float s = 0.f;
#pragma unroll
        for (int r = 0; r < 32; ++r) s = fmaf(kt[r][i], qt[r][j], s);
        acc[p] += s;
      }
    }
  }
  __syncthreads();
#pragma unroll
  for (int p = 0; p < 4; ++p) {
    int idx = tid + p*256;
    if (idx < 784) {
      int i = idx / 28, j = idx % 28;
      float nk = fmaxf(sqrtf(nks[b*224 + hd*28 + i]), 1e-12f);
      float nq = fmaxf(sqrtf(nqs[b*224 + hd*28 + j]), 1e-12f);
      sc[idx] = acc[p] * ATT_SCALE / (nk * nq);
    }
  }
  __syncthreads();
  if (tid < 28) {
    int i = tid;
    float mx = -1e30f;
#pragma unroll
    for (int j = 0; j < 28; ++j) mx = fmaxf(mx, sc[i*28+j]);
    float e[28]; float s = 0.f;
#pragma unroll
    for (int j = 0; j < 28; ++j) { e[j] = expf(sc[i*28+j] - mx); s += e[j]; }
    float inv = 1.f / s;
#pragma unroll
    for (int j = 0; j < 28; ++j) attnA[(size_t)blockIdx.x*784 + i*28 + j] = e[j]*inv;
  }
}

/* ------------- stage A: apply attention over channels + residual ------------- */
__global__ __launch_bounds__(256) void applyattn_kernel(const float* __restrict__ attnA, const float* __restrict__ kvb,
                                                        const float* __restrict__ x, float* __restrict__ x1) {
  const int bhd = blockIdx.x;
  const int b = bhd >> 3, hd = bhd & 7;
  const int tid = threadIdx.x;
  __shared__ float a[784];
  for (int idx = tid; idx < 784; idx += 256) a[idx] = attnA[(size_t)bhd*784 + idx];
  __syncthreads();
  const int i = tid % 28;
  const int n = blockIdx.y * 9 + tid / 28;
  if (tid < 252 && n < NTOK) {
    const float* vrow = &kvb[((size_t)(b*NTOK + n))*448 + 224 + hd*28];
    float s = 0.f;
#pragma unroll
    for (int j = 0; j < 28; ++j) s = fmaf(a[i*28+j], vrow[j], s);
    size_t o = ((size_t)(b*NTOK + n))*224 + hd*28 + i;
    x1[o] = s + x[o];
  }
}

/* ------------- mamba: LN + in_proj (xi half) ----- xi time-major [b][t][64] ------------- */
__global__ __launch_bounds__(256) void mamba_in_kernel(const float* __restrict__ x1, const float* __restrict__ lng,
                                                       const float* __restrict__ lnb, const float* __restrict__ Wip,
                                                       bf16* __restrict__ xi) {
  __shared__ float W[2048];
  __shared__ float g[32], bb[32];
  const int tid = threadIdx.x;
  const int b = blockIdx.y;
  const int t = blockIdx.x*256 + tid;
  for (int idx = tid; idx < 2048; idx += 256) {
    int m = idx >> 6, d = idx & 63;
    W[idx] = Wip[m*128 + d];
  }
  if (tid < 32) { g[tid] = lng[tid]; bb[tid] = lnb[tid]; }
  __syncthreads();
  float xv[32];
  float mean = 0.f;
#pragma unroll
  for (int m = 0; m < 32; ++m) { xv[m] = x1[((size_t)(b*32+m))*LSEQ + t]; mean += xv[m]; }
  mean *= (1.f/32.f);
  float var = 0.f;
#pragma unroll
  for (int m = 0; m < 32; ++m) { float d = xv[m]-mean; var = fmaf(d, d, var); }
  var *= (1.f/32.f);
  const float rstd = rsqrtf(var + 1e-5f);
  float xn[32];
#pragma unroll
  for (int m = 0; m < 32; ++m) xn[m] = (xv[m]-mean)*rstd*g[m] + bb[m];
  bf16* row = xi + ((size_t)b*LSEQ + t)*64;
#pragma unroll
  for (int gi = 0; gi < 8; ++gi) {
    float sv[8];
#pragma unroll
    for (int j = 0; j < 8; ++j) {
      int d = gi*8 + j;
      float s = 0.f;
#pragma unroll
      for (int m = 0; m < 32; ++m) s = fmaf(xn[m], W[m*64+d], s);
      sv[j] = s;
    }
    *(uint4*)(row + gi*8) = pack8f(sv);
  }
}

/* ------------- mamba: conv + silu + x_proj + dt --- LDS-tiled, 64 t per block ------------- */
__global__ __launch_bounds__(256) void mamba_conv_kernel(const bf16* __restrict__ xi, const float* __restrict__ convW,
    const float* __restrict__ convB, const float* __restrict__ xpW, const float* __restrict__ dtW,
    const float* __restrict__ dtB, bf16* __restrict__ xc, bf16* __restrict__ dts,
    bf16* __restrict__ Bc, bf16* __restrict__ Ccs) {
  __shared__ float xit[67][65];
  __shared__ float xct[64][65];
  __shared__ float xdbl[64][36];
  __shared__ float Wc[256], bcs[64], Wxp[2176], Wdt[128], bdt[64];
  const int tid = threadIdx.x;
  const int b = blockIdx.y;
  const int t0 = blockIdx.x * 64;

  if (tid < 256) Wc[tid] = convW[tid];
  for (int idx = tid; idx < 2176; idx += 256) Wxp[idx] = xpW[idx];
  if (tid < 128) Wdt[tid] = dtW[tid];
  if (tid < 64) { bcs[tid] = convB[tid]; bdt[tid] = dtB[tid]; }
  for (int idx = tid; idx < 67*8; idx += 256) {
    const int row = idx >> 3, seg = idx & 7;
    const int gt = t0 + row - 3;
    float f[8];
    if (gt >= 0) {
      uint4 q = *(const uint4*)(xi + ((size_t)b*LSEQ + gt)*64 + seg*8);
      unpack8(q, f);
    } else {
#pragma unroll
      for (int j = 0; j < 8; ++j) f[j] = 0.f;
    }
#pragma unroll
    for (int j = 0; j < 8; ++j) xit[row][seg*8 + j] = f[j];
  }
  __syncthreads();

  {
    const int tl = tid >> 2, cg = tid & 3;
    float sv[16];
#pragma unroll
    for (int j = 0; j < 16; ++j) {
      const int d = cg*16 + j;
      float s = bcs[d];
      s = fmaf(xit[tl+0][d], Wc[d*4+0], s);
      s = fmaf(xit[tl+1][d], Wc[d*4+1], s);
      s = fmaf(xit[tl+2][d], Wc[d*4+2], s);
      s = fmaf(xit[tl+3][d], Wc[d*4+3], s);
      s = s / (1.f + expf(-s));
      xct[tl][d] = s;
      sv[j] = s;
    }
    bf16* out = xc + ((size_t)b*LSEQ + t0 + tl)*64 + cg*16;
    *(uint4*)(out)     = pack8f(sv);
    *(uint4*)(out + 8) = pack8f(sv + 8);
  }
  __syncthreads();

  {
    const int tl = tid & 63, g = tid >> 6;
    for (int n = g; n < 34; n += 4) {
      float s = 0.f;
#pragma unroll
      for (int d = 0; d < 64; ++d) s = fmaf(xct[tl][d], Wxp[d*34 + n], s);
      xdbl[tl][n] = s;
    }
  }
  __syncthreads();

  if (tid < 256) {
    const int which = tid >> 7;
    const int idx = tid & 127;
    const int tl = idx >> 1, half = idx & 1;
    const float* src = &xdbl[tl][2 + which*16 + half*8];
    bf16* dst = (which ? Ccs : Bc) + ((size_t)b*LSEQ + t0 + tl)*16 + half*8;
    *(uint4*)dst = pack8f(src);
  }
  {
    const int tl = tid >> 2, cg = tid & 3;
    const float x0 = xdbl[tl][0], x1v = xdbl[tl][1];
    float sv[16];
#pragma unroll
    for (int j = 0; j < 16; ++j) {
      const int d = cg*16 + j;
      float v = fmaf(x0, Wdt[d], fmaf(x1v, Wdt[64+d], bdt[d]));
      v = (v > 20.f) ? v : log1pf(expf(v));
      sv[j] = v;
    }
    bf16* out = dts + ((size_t)b*LSEQ + t0 + tl)*64 + cg*16;
    *(uint4*)(out)     = pack8f(sv);
    *(uint4*)(out + 8) = pack8f(sv + 8);
  }
}

/* ------------- scan pass 1 ------------- */
__global__ __launch_bounds__(256) void scan1_kernel(const bf16* __restrict__ dts, const bf16* __restrict__ xc,
    const bf16* __restrict__ Bc, const float* __restrict__ Alog, float* __restrict__ P, float* __restrict__ F) {
  const int w = blockIdx.x*4 + (threadIdx.x >> 6);
  const int d = threadIdx.x & 63;
  const int b = w >> 6, chk = w & 63;
  float A[16];
#pragma unroll
  for (int n = 0; n < 16; ++n) A[n] = -expf(Alog[d*16+n]);
  float Pr[16], Fr[16];
#pragma unroll
  for (int n = 0; n < 16; ++n) { Pr[n] = 1.f; Fr[n] = 0.f; }
  const size_t tbase = (size_t)b*LSEQ + (size_t)chk*CHLEN;
  for (int i = 0; i < CHLEN; ++i) {
    const size_t t = tbase + i;
    float dtv = b2f(dts[t*64 + d]);
    float u   = b2f(xc [t*64 + d]);
    float du  = dtv*u;
    const uint4* bp = (const uint4*)(Bc + t*16);
    float Bv[16]; unpack8(bp[0], Bv); unpack8(bp[1], Bv+8);
#pragma unroll
    for (int n = 0; n < 16; ++n) {
      float a = expf(dtv*A[n]);
      Pr[n] *= a;
      Fr[n] = fmaf(a, Fr[n], du*Bv[n]);
    }
  }
  const size_t o = (((size_t)(b*64 + chk))*64 + d)*16;
  float4* Pp = (float4*)(P + o);
  float4* Fp = (float4*)(F + o);
#pragma unroll
  for (int q = 0; q < 4; ++q) {
    Pp[q] = make_float4(Pr[4*q], Pr[4*q+1], Pr[4*q+2], Pr[4*q+3]);
    Fp[q] = make_float4(Fr[4*q], Fr[4*q+1], Fr[4*q+2], Fr[4*q+3]);
  }
}

/* ------------- scan pass 2 ------------- */
__global__ __launch_bounds__(256) void scan2_kernel(const float* __restrict__ P, const float* __restrict__ F,
                                                    float* __restrict__ H0) {
  const int idx = blockIdx.x*256 + threadIdx.x;
  const int b = idx >> 10, dn = idx & 1023;
  const size_t base = (size_t)b*64*1024 + dn;
  float h = 0.f;
  for (int ch = 0; ch < 64; ++ch) {
    const size_t a = base + (size_t)ch*1024;
    H0[a] = h;
    h = fmaf(P[a], h, F[a]);
  }
}

/* ------------- scan pass 3 ------------- */
__global__ __launch_bounds__(256) void scan3_kernel(const bf16* __restrict__ dts, const bf16* __restrict__ xc,
    const bf16* __restrict__ Bc, const bf16* __restrict__ Ccs, const float* __restrict__ Alog,
    const float* __restrict__ Dp, const float* __restrict__ H0, bf16* __restrict__ y) {
  const int w = blockIdx.x*4 + (threadIdx.x >> 6);
  const int d = threadIdx.x & 63;
  const int b = w >> 6, chk = w & 63;
  float A[16];
#pragma unroll
  for (int n = 0; n < 16; ++n) A[n] = -expf(Alog[d*16+n]);
  float h[16];
  const size_t hb = (((size_t)(b*64 + chk))*64 + d)*16;
  const float4* Hp = (const float4*)(H0 + hb);
#pragma unroll
  for (int q = 0; q < 4; ++q) {
    float4 v = Hp[q];
    h[4*q] = v.x; h[4*q+1] = v.y; h[4*q+2] = v.z; h[4*q+3] = v.w;
  }
  const float Dpd = Dp[d];
  const size_t tbase = (size_t)b*LSEQ + (size_t)chk*CHLEN;
  for (int i = 0; i < CHLEN; ++i) {
    const size_t t = tbase + i;
    float dtv = b2f(dts[t*64 + d]);
    float u   = b2f(xc [t*64 + d]);
    float du  = dtv*u;
    const uint4* bp = (const uint4*)(Bc  + t*16);
    const uint4* cp = (const uint4*)(Ccs + t*16);
    float Bv[16], Cv[16];
    unpack8(bp[0], Bv); unpack8(bp[1], Bv+8);
    unpack8(cp[0], Cv); unpack8(cp[1], Cv+8);
    float yv = 0.f;
#pragma unroll
    for (int n = 0; n < 16; ++n) {
      float a = expf(dtv*A[n]);
      h[n] = fmaf(a, h[n], du*Bv[n]);
      yv = fmaf(h[n], Cv[n], yv);
    }
    y[t*64 + d] = f2b(yv + u*Dpd);
  }
}

/* ------------- mamba tail ------------- */
__global__ __launch_bounds__(256) void mamba_out_kernel(float* __restrict__ x1, const bf16* __restrict__ y,
    const float* __restrict__ lng, const float* __restrict__ lnb, const float* __restrict__ Wip,
    const float* __restrict__ Wout, const float* __restrict__ skipp, const float* __restrict__ Wp,
    const float* __restrict__ pbias) {
  __shared__ float Wz[2048];
  __shared__ float Wo[2048];
  __shared__ float Pw[1024];
  __shared__ float g[32], bb[32], pb[32];
  __shared__ float sskip;
  const int tid = threadIdx.x;
  for (int idx = tid; idx < 2048; idx += 256) {
    int m = idx >> 6, d = idx & 63;
    Wz[m*64+d] = Wip[m*128 + 64 + d];
  }
  for (int idx = tid; idx < 2048; idx += 256) Wo[idx] = Wout[idx];
  for (int idx = tid; idx < 1024; idx += 256) Pw[idx] = Wp[idx];
  if (tid < 32) { g[tid] = lng[tid]; bb[tid] = lnb[tid]; pb[tid] = pbias[tid]; }
  if (tid == 0) sskip = skipp[0];
  __syncthreads();
  const int b = blockIdx.y;
  const int t = blockIdx.x*256 + tid;
  float xv[32];
  float mean = 0.f;
#pragma unroll
  for (int m = 0; m < 32; ++m) { xv[m] = x1[((size_t)(b*32+m))*LSEQ + t]; mean += xv[m]; }
  mean *= (1.f/32.f);
  float var = 0.f;
#pragma unroll
  for (int m = 0; m < 32; ++m) { float d = xv[m]-mean; var = fmaf(d, d, var); }
  var *= (1.f/32.f);
  const float rstd = rsqrtf(var + 1e-5f);
  float xn[32];
#pragma unroll
  for (int m = 0; m < 32; ++m) xn[m] = (xv[m]-mean)*rstd*g[m] + bb[m];
  float out[32] = {};
  const bf16* yrow = y + ((size_t)b*LSEQ + t)*64;
#pragma unroll
  for (int gi = 0; gi < 8; ++gi) {
    uint4 q = *(const uint4*)(yrow + gi*8);
    float yv8[8]; unpack8(q, yv8);
#pragma unroll
    for (int j = 0; j < 8; ++j) {
      int d = gi*8 + j;
      float zd = 0.f;
#pragma unroll
      for (int m = 0; m < 32; ++m) zd = fmaf(xn[m], Wz[m*64+d], zd);
      float gd = yv8[j] * zd / (1.f + expf(-zd));
#pragma unroll
      for (int m = 0; m < 32; ++m) out[m] = fmaf(gd, Wo[d*32+m], out[m]);
    }
  }
#pragma unroll
  for (int m = 0; m < 32; ++m) out[m] = fmaf(sskip, xn[m], out[m]);
  float mean2 = 0.f;
#pragma unroll
  for (int m = 0; m < 32; ++m) mean2 += out[m];
  mean2 *= (1.f/32.f);
  float var2 = 0.f;
#pragma unroll
  for (int m = 0; m < 32; ++m) { float d = out[m]-mean2; var2 = fmaf(d, d, var2); }
  var2 *= (1.f/32.f);
  const float rstd2 = rsqrtf(var2 + 1e-5f);
#pragma unroll
  for (int m = 0; m < 32; ++m) out[m] = (out[m]-mean2)*rstd2*g[m] + bb[m];
  for (int m2 = 0; m2 < 32; ++m2) {
    float r = pb[m2];
#pragma unroll
    for (int m = 0; m < 32; ++m) r = fmaf(out[m], Pw[m*32+m2], r);
    x1[((size_t)(b*32+m2))*LSEQ + t] = r + xv[m2];
  }
}

/* ------------- 5x5x5 conv, register-blocked: 8 k-outputs per thread ------------- */
__global__ __launch_bounds__(256) void conv3d_kernel(const float* __restrict__ x2, const float* __restrict__ w,
                                                     const float* __restrict__ bias, float* __restrict__ x3) {
  __shared__ float ww[125];
  __shared__ float b0;
  const int tid = threadIdx.x;
  if (tid < 125) ww[tid] = w[tid];
  if (tid == 0) b0 = bias[0];
  __syncthreads();
  const int gid = blockIdx.x*256 + tid;   // 1,146,880 work items
  const int kg = gid % 28;
  int r = gid / 28;
  const int j = r % 40; r /= 40;
  const int i = r % 32; const int b = r / 32;
  const int k0 = kg * 8;
  float acc[8] = {};
  for (int di = 0; di < 5; ++di) {
    int ii = i + di - 2; if (ii < 0 || ii >= 32) continue;
    for (int dj = 0; dj < 5; ++dj) {
      int jj = j + dj - 2; if (jj < 0 || jj >= 40) continue;
      const float* row = &x2[(((size_t)(b*32+ii))*40 + jj)*224];
      float f[16];
#pragma unroll
      for (int off = 0; off < 4; ++off) {
        int base = k0 + off*4 - 4;
        if (base >= 0 && base <= 220) {
          float4 v = *(const float4*)(row + base);
          f[off*4+0]=v.x; f[off*4+1]=v.y; f[off*4+2]=v.z; f[off*4+3]=v.w;
        } else {
          f[off*4+0]=0.f; f[off*4+1]=0.f; f[off*4+2]=0.f; f[off*4+3]=0.f;
        }
      }
      const float* wr = &ww[(di*5+dj)*5];
#pragma unroll
      for (int dk = 0; dk < 5; ++dk) {
        float wv = wr[dk];
#pragma unroll
        for (int o = 0; o < 8; ++o) acc[o] = fmaf(wv, f[o+dk+2], acc[o]);
      }
    }
  }
  float* out = x3 + (size_t)gid*8;
  *(float4*)(out)     = make_float4(acc[0]+b0, acc[1]+b0, acc[2]+b0, acc[3]+b0);
  *(float4*)(out + 4) = make_float4(acc[4]+b0, acc[5]+b0, acc[6]+b0, acc[7]+b0);
}

/* ------------- DWT + reflect-pad + window partition ------------- */
__global__ __launch_bounds__(256) void dwtwin_kernel(const float* __restrict__ x3, bf16* __restrict__ xw) {
  const int gid = blockIdx.x*256 + threadIdx.x;
  const int ch = gid % 224; int r = gid / 224;
  const int tok = r % 64; const int win = r / 64;
  const int b = win / 6, rr = win % 6, wy = rr / 3, wx = rr % 3;
  const int ty = tok >> 3, tx = tok & 7;
  const int i = wy*8 + ty;
  const int jp = wx*8 + tx;
  const int j = (jp < 20) ? jp : (38 - jp);
  const size_t base = (((size_t)(b*32 + 2*i))*40 + 2*j)*224 + ch;
  const float v00 = x3[base];
  const float v01 = x3[base + 224];
  const float v10 = x3[base + 8960];
  const float v11 = x3[base + 8960 + 224];
  const size_t o = (size_t)r*224 + ch;
  const size_t SW = 2752512;
  xw[o]        = f2b(0.5f*(v00 + v01 + v10 + v11));
  xw[SW + o]   = f2b(0.5f*(v00 + v01 - v10 - v11));
  xw[2*SW + o] = f2b(0.5f*(v00 - v01 + v10 - v11));
  xw[3*SW + o] = f2b(0.5f*(v00 - v01 - v10 + v11));
}

/* ------------- window attention per (window, head); emits bf16 ------------- */
__global__ __launch_bounds__(256) void winattn_kernel(const float* __restrict__ qw, const float* __restrict__ kvw,
                                                      const float* __restrict__ pos, bf16* __restrict__ ow) {
  const int win = blockIdx.x >> 3, hd = blockIdx.x & 7;
  const int tid = threadIdx.x;
  __shared__ float qs[1792], ks[1792], vs[1792];
  __shared__ float sc[4096];
  for (int idx = tid; idx < 1792; idx += 256) {
    int tok = idx / 28, d = idx % 28;
    qs[idx] = qw [((size_t)(win*64+tok))*224 + hd*28 + d] * ATT_SCALE;
    ks[idx] = kvw[((size_t)(win*64+tok))*448 + hd*28 + d];
    vs[idx] = kvw[((size_t)(win*64+tok))*448 + 224 + hd*28 + d];
  }
  __syncthreads();
#pragma unroll
  for (int p = 0; p < 16; ++p) {
    int idx = tid + p*256;
    int i = idx >> 6, j = idx & 63;
    float a = 0.f;
#pragma unroll
    for (int d = 0; d < 28; ++d) a = fmaf(qs[i*28+d], ks[j*28+d], a);
    sc[idx] = a + pos[(hd*64 + i)*64 + j];
  }
  __syncthreads();
  if (tid < 64) {
    const int i = tid;
    float mx = -1e30f;
#pragma unroll
    for (int j = 0; j < 64; ++j) mx = fmaxf(mx, sc[i*64+j]);
    float s = 0.f;
#pragma unroll
    for (int j = 0; j < 64; ++j) { float e = expf(sc[i*64+j] - mx); sc[i*64+j] = e; s += e; }
    const float inv = 1.f / s;
#pragma unroll
    for (int j = 0; j < 64; ++j) sc[i*64+j] *= inv;
  }
  __syncthreads();
  for (int idx = tid; idx < 1792; idx += 256) {
    int i = idx / 28, d = idx % 28;
    float a = 0.f;
#pragma unroll
    for (int j = 0; j < 64; ++j) a = fmaf(sc[i*64+j], vs[j*28+d], a);
    ow[((size_t)(win*64+i))*224 + hd*28 + d] = f2b(a);
  }
}

/* ------------- un-window + bias, drop pad ------------- */
__global__ __launch_bounds__(256) void scatter_kernel(const float* __restrict__ proj, const float* __restrict__ bo,
                                                      float* __restrict__ wa) {
  const int gid = blockIdx.x*256 + threadIdx.x;
  const int ch = gid % 224; int r = gid / 224;
  const int tok = r % 64; const int win = r / 64;
  const int b = win / 6, rr = win % 6, wy = rr / 3, wx = rr % 3;
  const int ty = tok >> 3, tx = tok & 7;
  const int i = wy*8 + ty;
  const int jp = wx*8 + tx;
  if (jp < 20)
    wa[(((size_t)(b*16+i))*20 + jp)*224 + ch] = proj[gid] + bo[ch];
}

/* ------------- inverse Haar + final transpose ------------- */
__global__ __launch_bounds__(256) void iwt_kernel(const float* __restrict__ wa, float* __restrict__ out) {
  const int gid = blockIdx.x*256 + threadIdx.x;
  const int ch = gid % 224; int r = gid / 224;
  const int j2 = r % 40; r /= 40;
  const int i2 = r % 32; const int b = r / 32;
  const size_t SB = 2293760;
  const size_t base = (((size_t)(b*16 + (i2>>1)))*20 + (j2>>1))*224 + ch;
  const float cA = wa[base];
  const float cH = wa[SB + base];
  const float cV = wa[2*SB + base];
  const float cD = wa[3*SB + base];
  const float sp = (i2 & 1) ? -1.f : 1.f;
  const float sq = (j2 & 1) ? -1.f : 1.f;
  out[gid] = 0.5f*(cA + sp*cH + sq*cV + sp*sq*cD);
}

/* =============================== launcher =============================== */
extern "C" void kernel_launch(void* const* d_in, const int* in_sizes, int n_in,
                              void* d_out, int out_size, void* d_ws, size_t ws_size,
                              hipStream_t stream) {
  (void)in_sizes; (void)n_in; (void)out_size; (void)ws_size;
  const float* x     = (const float*)d_in[0];
  const float* Wq    = (const float*)d_in[1];
  const float* Wkv   = (const float*)d_in[2];
  const float* lng   = (const float*)d_in[3];
  const float* lnb   = (const float*)d_in[4];
  const float* Wip   = (const float*)d_in[5];
  const float* convW = (const float*)d_in[6];
  const float* convB = (const float*)d_in[7];
  const float* xpW   = (const float*)d_in[8];
  const float* dtW   = (const float*)d_in[9];
  const float* dtB   = (const float*)d_in[10];
  const float* Alog  = (const float*)d_in[11];
  const float* Dp    = (const float*)d_in[12];
  const float* Wout  = (const float*)d_in[13];
  const float* skip  = (const float*)d_in[14];
  const float* Wp    = (const float*)d_in[15];
  const float* pbias = (const float*)d_in[16];
  const float* c3w   = (const float*)d_in[17];
  const float* c3b   = (const float*)d_in[18];
  const float* Wq1   = (const float*)d_in[19];
  const float* Wkv1  = (const float*)d_in[20];
  const float* pos   = (const float*)d_in[21];

  char* ws = (char*)d_ws;
  /* phased overlays; peak 191,176,704 B */
  float* x1    = (float*)(ws + 0);             // 36.7MB; later wa
  float* qbuf  = (float*)(ws + 36700160);
  float* kvbuf = (float*)(ws + 73400320);      // ends 146,800,640
  bf16*  WqT   = (bf16*) (ws + 146800640);     // 224x224 bf16 (stage A only)
  bf16*  WkvT  = (bf16*) (ws + 146900992);     // 448x224 bf16 (stage A only)
  bf16*  xbf   = (bf16*) (ws + 147101696);     // 40960x224 bf16 (stage A only), ends 165,451,776
  bf16*  xi    = (bf16*) (ws + 36700160);      // phase B [b][t][64]
  bf16*  xc    = (bf16*) (ws + 73400320);      // [b][t][64]
  bf16*  dts   = (bf16*) (ws + 110100480);     // [b][t][64]
  bf16*  Bcb   = (bf16*) (ws + 146800640);     // [b][t][16]
  bf16*  Ccb   = (bf16*) (ws + 155975680);     // [b][t][16]
  float* Pbuf  = (float*)(ws + 165150720);
  float* Fbuf  = (float*)(ws + 173539328);
  float* H0    = (float*)(ws + 181927936);
  bf16*  ybuf  = (bf16*) (ws + 36700160);      // over xi
  float* x3    = (float*)(ws + 36700160);      // over ybuf
  bf16*  xw    = (bf16*) (ws + 73400320);      // 4 subbands, ends 95,420,416
  float* qw    = (float*)(ws + 95420416);
  float* kvw   = (float*)(ws + 106430464);     // ends 128,450,560
  bf16*  owb   = (bf16*) (ws + 128450560);     // 12288x224 bf16, ends 133,955,584
  bf16*  Wq1T  = (bf16*) (ws + 134000640);     // stage D weights (region dead)
  bf16*  Wkv1T = (bf16*) (ws + 134100992);
  bf16*  WoT0  = (bf16*) (ws + 134301696);
  bf16*  WoT1  = (bf16*) (ws + 134402048);
  bf16*  WoT2  = (bf16*) (ws + 134502400);
  bf16*  WoT3  = (bf16*) (ws + 134602752);
  float* projt = qw;
  float* wab   = (float*)(ws + 0);
  float* nqs   = (float*)(ws + 190316544);
  float* nks   = (float*)(ws + 190345216);
  float* attnA = (float*)(ws + 190373888);
  bf16* WoTs[4] = {WoT0, WoT1, WoT2, WoT3};

  /* -------- stage A: transposed cosine attention (MFMA GEMMs) -------- */
  zero_kernel<<<56, 256, 0, stream>>>(nqs, 14336);
  cvt_bf16_kernel<<<4480, 256, 0, stream>>>(x, xbf, 1146880);
  transpose_bf16_kernel<<<196, 256, 0, stream>>>(Wq,  WqT,  224, 224);
  transpose_bf16_kernel<<<392, 256, 0, stream>>>(Wkv, WkvT, 224, 448);
  mfma_gemm_kernel<<<dim3(4,640), 256, 0, stream>>>(xbf, WqT,  qbuf,  40960, 224, 224);
  mfma_gemm_kernel<<<dim3(7,640), 256, 0, stream>>>(xbf, WkvT, kvbuf, 40960, 448, 224);
  colnorm_kernel<<<512, 256, 0, stream>>>(qbuf, kvbuf, nqs, nks);
  gram_kernel<<<256, 256, 0, stream>>>(qbuf, kvbuf, nqs, nks, attnA);
  applyattn_kernel<<<dim3(256,143), 256, 0, stream>>>(attnA, kvbuf, x, x1);

  /* -------- stage B: LN + mamba + LN/proj residual -------- */
  mamba_in_kernel<<<dim3(35,32), 256, 0, stream>>>(x1, lng, lnb, Wip, xi);
  mamba_conv_kernel<<<dim3(140,32), 256, 0, stream>>>(xi, convW, convB, xpW, dtW, dtB, xc, dts, Bcb, Ccb);
  scan1_kernel<<<512, 256, 0, stream>>>(dts, xc, Bcb, Alog, Pbuf, Fbuf);
  scan2_kernel<<<128, 256, 0, stream>>>(Pbuf, Fbuf, H0);
  scan3_kernel<<<512, 256, 0, stream>>>(dts, xc, Bcb, Ccb, Alog, Dp, H0, ybuf);
  mamba_out_kernel<<<dim3(35,32), 256, 0, stream>>>(x1, ybuf, lng, lnb, Wip, Wout, skip, Wp, pbias);

  /* -------- stage C: 5x5x5 conv -------- */
  conv3d_kernel<<<4480, 256, 0, stream>>>(x1, c3w, c3b, x3);

  /* -------- stage D: DWT + 4x window attention + IWT -------- */
  dwtwin_kernel<<<10752, 256, 0, stream>>>(x3, xw);
  transpose_bf16_kernel<<<196, 256, 0, stream>>>(Wq1,  Wq1T,  224, 224);
  transpose_bf16_kernel<<<392, 256, 0, stream>>>(Wkv1, Wkv1T, 224, 448);
  for (int s = 0; s < 4; ++s)
    transpose_bf16_kernel<<<196, 256, 0, stream>>>((const float*)d_in[22 + 2*s], WoTs[s], 224, 224);
  for (int s = 0; s < 4; ++s) {
    const float* bo = (const float*)d_in[23 + 2*s];
    const bf16* xws = xw + (size_t)s * 2752512;
    mfma_gemm_kernel<<<dim3(4,192), 256, 0, stream>>>(xws, Wq1T,  qw,  12288, 224, 224);
    mfma_gemm_kernel<<<dim3(7,192), 256, 0, stream>>>(xws, Wkv1T, kvw, 12288, 448, 224);
    winattn_kernel<<<1536, 256, 0, stream>>>(qw, kvw, pos, owb);
    mfma_gemm_kernel<<<dim3(4,192), 256, 0, stream>>>(owb, WoTs[s], projt, 12288, 224, 224);
    scatter_kernel<<<10752, 256, 0, stream>>>(projt, bo, wab + (size_t)s * 2293760);
  }
  iwt_kernel<<<35840, 256, 0, stream>>>(wab, (float*)d_out);
}